// Round 2
// baseline (726.972 us; speedup 1.0000x reference)
//
#include <hip/hip_runtime.h>
#include <math.h>

#define N_NODES 2048
#define N_EDGES 4096
#define DIM 128
#define HEADS 4
#define DH 32
#define NCLS 16
#define TOPK 1024

__device__ __forceinline__ float wave_reduce_sum(float v) {
#pragma unroll
  for (int o = 32; o > 0; o >>= 1) v += __shfl_xor(v, o, 64);
  return v;
}

// ---------------- Router: scores + gated features (nodes then edges) --------
__global__ __launch_bounds__(256) void router_kernel(
    const float* __restrict__ nf, const float* __restrict__ ef,
    const float* __restrict__ w_rn, const float* __restrict__ b_rn,
    const float* __restrict__ w_re, const float* __restrict__ b_re,
    float* __restrict__ ns, float* __restrict__ es,
    float* __restrict__ xn, float* __restrict__ xe) {
  int wid = threadIdx.x >> 6, lane = threadIdx.x & 63;
  int row = blockIdx.x * 4 + wid;
  const float* feat;
  const float* w;
  float b;
  float* scp;
  float* xp;
  if (row < N_NODES) {
    feat = nf + (size_t)row * DIM;
    w = w_rn; b = b_rn[0];
    scp = ns + row; xp = xn + (size_t)row * DIM;
  } else {
    int r = row - N_NODES;
    feat = ef + (size_t)r * DIM;
    w = w_re; b = b_re[0];
    scp = es + r; xp = xe + (size_t)r * DIM;
  }
  float f0 = feat[lane], f1 = feat[lane + 64];
  float d = f0 * w[lane] + f1 * w[lane + 64];
  d = wave_reduce_sum(d);
  float sc = 1.0f / (1.0f + __expf(-(d + b)));
  xp[lane] = f0 * sc;
  xp[lane + 64] = f1 * sc;
  if (lane == 0) *scp = sc;
}

// ---------------- Top-k threshold + node mask (single block) ----------------
// kth largest t = max{v : count(s >= v) >= k}; binary search over float bit
// patterns (sigmoid scores are in (0,1) -> positive -> bit order == value
// order). Midpoint computed in 64-bit: the naive (hi-lo+1) overflowed u32 on
// round 1 and hung the GPU (mid==lo==0 forever).
__global__ __launch_bounds__(1024) void topk_mask_kernel(
    const float* __restrict__ ns, int* __restrict__ mask,
    float* __restrict__ thr_out) {
  __shared__ int cnt;
  int tid = threadIdx.x;
  unsigned b0 = __float_as_uint(ns[tid]);
  unsigned b1 = __float_as_uint(ns[tid + 1024]);
  unsigned lo = 0u, hi = 0x3F800000u;  // scores < 1.0f
  while (lo < hi) {
    unsigned mid = (unsigned)(((unsigned long long)lo + hi + 1ull) >> 1);
    if (tid == 0) cnt = 0;
    __syncthreads();
    int c = (b0 >= mid) + (b1 >= mid);
#pragma unroll
    for (int o = 1; o < 64; o <<= 1) c += __shfl_xor(c, o, 64);
    if ((tid & 63) == 0) atomicAdd(&cnt, c);
    __syncthreads();
    int total = cnt;
    __syncthreads();  // protect cnt before next iteration's reset
    if (total >= TOPK) lo = mid; else hi = mid - 1;
  }
  mask[tid] = (b0 >= lo) ? 1 : 0;
  mask[tid + 1024] = (b1 >= lo) ? 1 : 0;
  if (tid == 0) thr_out[0] = __uint_as_float(lo);
}

// ---------------- Generic f32 GEMM: C = A[M,K]@B[K,N] + bias (opt. GELU) ----
template <int EPI>  // 0 = none, 1 = tanh-approx GELU
__global__ __launch_bounds__(256) void gemm_kernel(
    const float* __restrict__ A, const float* __restrict__ B,
    const float* __restrict__ bias, float* __restrict__ C,
    int M, int N, int K) {
  __shared__ float As[16][65];
  __shared__ float Bs[16][65];
  int bm = blockIdx.x * 64, bn = blockIdx.y * 64;
  int tid = threadIdx.x;
  int tm = (tid >> 4) * 4, tn = (tid & 15) * 4;
  float acc[4][4] = {};
  for (int k0 = 0; k0 < K; k0 += 16) {
#pragma unroll
    for (int i = 0; i < 4; i++) {
      int e = i * 256 + tid;
      int r = e >> 4, kk = e & 15;
      As[kk][r] = A[(size_t)(bm + r) * K + k0 + kk];
      int kb = e >> 6, c = e & 63;
      Bs[kb][c] = B[(size_t)(k0 + kb) * N + bn + c];
    }
    __syncthreads();
#pragma unroll
    for (int kk = 0; kk < 16; kk++) {
      float a[4], bv[4];
#pragma unroll
      for (int i = 0; i < 4; i++) a[i] = As[kk][tm + i];
#pragma unroll
      for (int j = 0; j < 4; j++) bv[j] = Bs[kk][tn + j];
#pragma unroll
      for (int i = 0; i < 4; i++)
#pragma unroll
        for (int j = 0; j < 4; j++) acc[i][j] = fmaf(a[i], bv[j], acc[i][j]);
    }
    __syncthreads();
  }
#pragma unroll
  for (int i = 0; i < 4; i++) {
#pragma unroll
    for (int j = 0; j < 4; j++) {
      float v = acc[i][j] + bias[bn + tn + j];
      if (EPI == 1) {
        float u = 0.7978845608028654f * (v + 0.044715f * v * v * v);
        v = 0.5f * v * (1.0f + tanhf(u));
      }
      C[(size_t)(bm + tm + i) * N + bn + tn + j] = v;
    }
  }
}

// ---------------- Gather GEMM: C = (NO[src]+NO[dst])@B + bias + EO ----------
__global__ __launch_bounds__(256) void gemm_msg_kernel(
    const float* __restrict__ NO, const int* __restrict__ src,
    const int* __restrict__ dst, const float* __restrict__ B,
    const float* __restrict__ bias, const float* __restrict__ EO,
    float* __restrict__ C) {
  __shared__ float As[16][65];
  __shared__ float Bs[16][65];
  int bm = blockIdx.x * 64, bn = blockIdx.y * 64;
  int tid = threadIdx.x;
  int tm = (tid >> 4) * 4, tn = (tid & 15) * 4;
  float acc[4][4] = {};
  for (int k0 = 0; k0 < DIM; k0 += 16) {
#pragma unroll
    for (int i = 0; i < 4; i++) {
      int e = i * 256 + tid;
      int r = e >> 4, kk = e & 15;
      int row = bm + r;
      int s0 = src[row], d0 = dst[row];
      As[kk][r] = NO[(size_t)s0 * DIM + k0 + kk] + NO[(size_t)d0 * DIM + k0 + kk];
      int kb = e >> 6, c = e & 63;
      Bs[kb][c] = B[(size_t)(k0 + kb) * DIM + bn + c];
    }
    __syncthreads();
#pragma unroll
    for (int kk = 0; kk < 16; kk++) {
      float a[4], bv[4];
#pragma unroll
      for (int i = 0; i < 4; i++) a[i] = As[kk][tm + i];
#pragma unroll
      for (int j = 0; j < 4; j++) bv[j] = Bs[kk][tn + j];
#pragma unroll
      for (int i = 0; i < 4; i++)
#pragma unroll
        for (int j = 0; j < 4; j++) acc[i][j] = fmaf(a[i], bv[j], acc[i][j]);
    }
    __syncthreads();
  }
#pragma unroll
  for (int i = 0; i < 4; i++) {
#pragma unroll
    for (int j = 0; j < 4; j++) {
      size_t idx = (size_t)(bm + tm + i) * DIM + bn + tn + j;
      C[idx] = acc[i][j] + bias[bn + tn + j] + EO[idx];
    }
  }
}

// ---------------- Node attention (key mask), flash-style --------------------
__global__ __launch_bounds__(256) void attn_node_kernel(
    const float* __restrict__ Q, const float* __restrict__ Km,
    const float* __restrict__ V, const int* __restrict__ mask,
    float* __restrict__ O) {
  __shared__ float Ks[64][33];
  __shared__ float Vs[64][33];
  __shared__ float ored[4][32];
  int h = blockIdx.y;
  int wid = threadIdx.x >> 6, lane = threadIdx.x & 63;
  int qi = blockIdx.x * 4 + wid;
  const float* qp = Q + (size_t)qi * DIM + h * DH;
  float qv[DH];
#pragma unroll
  for (int d = 0; d < DH; d++) qv[d] = qp[d];
  float m = -INFINITY, s = 0.f;
  float acc[DH];
#pragma unroll
  for (int d = 0; d < DH; d++) acc[d] = 0.f;

  for (int t0 = 0; t0 < N_NODES; t0 += 64) {
#pragma unroll
    for (int i = 0; i < 8; i++) {
      int e = i * 256 + threadIdx.x;
      int r = e >> 5, d = e & 31;
      Ks[r][d] = Km[(size_t)(t0 + r) * DIM + h * DH + d];
      Vs[r][d] = V[(size_t)(t0 + r) * DIM + h * DH + d];
    }
    __syncthreads();
    if (mask[t0 + lane]) {
      float sc = 0.f;
#pragma unroll
      for (int d = 0; d < DH; d++) sc = fmaf(qv[d], Ks[lane][d], sc);
      sc *= 0.17677669529663687f;  // 1/sqrt(32)
      if (sc > m) {
        float alpha = __expf(m - sc);  // exp(-inf)=0 on first hit
        s = s * alpha + 1.0f;
#pragma unroll
        for (int d = 0; d < DH; d++) acc[d] = fmaf(acc[d], alpha, Vs[lane][d]);
        m = sc;
      } else {
        float p = __expf(sc - m);
        s += p;
#pragma unroll
        for (int d = 0; d < DH; d++) acc[d] = fmaf(p, Vs[lane][d], acc[d]);
      }
    }
    __syncthreads();
  }
  // merge the 64 per-lane partial softmaxes
  float mg = m;
#pragma unroll
  for (int o = 32; o > 0; o >>= 1) mg = fmaxf(mg, __shfl_xor(mg, o, 64));
  float f = (m == -INFINITY) ? 0.f : __expf(m - mg);
  float sg = wave_reduce_sum(s * f);
  float inv = 1.0f / sg;
#pragma unroll
  for (int d = 0; d < DH; d++) {
    float v = acc[d] * f;
#pragma unroll
    for (int o = 32; o > 0; o >>= 1) v += __shfl_xor(v, o, 64);
    acc[d] = v;
  }
  if (lane == 0) {
#pragma unroll
    for (int d = 0; d < DH; d++) ored[wid][d] = acc[d] * inv;
  }
  __syncthreads();
  if (lane < DH) O[(size_t)qi * DIM + h * DH + lane] = ored[wid][lane];
}

// ---------------- Edge attention (line-graph adjacency), sparse -------------
__global__ __launch_bounds__(256) void attn_edge_kernel(
    const float* __restrict__ Q, const float* __restrict__ Km,
    const float* __restrict__ V, const int* __restrict__ src,
    const int* __restrict__ dst, float* __restrict__ O) {
  __shared__ int sks[256];
  __shared__ int dks[256];
  __shared__ float ored[4][32];
  int h = blockIdx.y;
  int wid = threadIdx.x >> 6, lane = threadIdx.x & 63;
  int qi = blockIdx.x * 4 + wid;
  int sq = src[qi], dq = dst[qi];
  const float* qp = Q + (size_t)qi * DIM + h * DH;
  float qv[DH];
#pragma unroll
  for (int d = 0; d < DH; d++) qv[d] = qp[d];
  float m = -INFINITY, s = 0.f;
  float acc[DH];
#pragma unroll
  for (int d = 0; d < DH; d++) acc[d] = 0.f;

  for (int t0 = 0; t0 < N_EDGES; t0 += 256) {
    sks[threadIdx.x] = src[t0 + threadIdx.x];
    dks[threadIdx.x] = dst[t0 + threadIdx.x];
    __syncthreads();
#pragma unroll
    for (int ii = 0; ii < 4; ii++) {
      int jj = ii * 64 + lane;
      int sk = sks[jj], dk = dks[jj];
      if (sk == sq || sk == dq || dk == sq || dk == dq) {
        int j = t0 + jj;
        const float* kp = Km + (size_t)j * DIM + h * DH;
        const float* vp = V + (size_t)j * DIM + h * DH;
        float sc = 0.f;
#pragma unroll
        for (int d = 0; d < DH; d++) sc = fmaf(qv[d], kp[d], sc);
        sc *= 0.17677669529663687f;
        if (sc > m) {
          float alpha = __expf(m - sc);
          s = s * alpha + 1.0f;
#pragma unroll
          for (int d = 0; d < DH; d++) acc[d] = fmaf(acc[d], alpha, vp[d]);
          m = sc;
        } else {
          float p = __expf(sc - m);
          s += p;
#pragma unroll
          for (int d = 0; d < DH; d++) acc[d] = fmaf(p, vp[d], acc[d]);
        }
      }
    }
    __syncthreads();
  }
  float mg = m;
#pragma unroll
  for (int o = 32; o > 0; o >>= 1) mg = fmaxf(mg, __shfl_xor(mg, o, 64));
  float f = (m == -INFINITY) ? 0.f : __expf(m - mg);
  float sg = wave_reduce_sum(s * f);
  float inv = 1.0f / sg;
#pragma unroll
  for (int d = 0; d < DH; d++) {
    float v = acc[d] * f;
#pragma unroll
    for (int o = 32; o > 0; o >>= 1) v += __shfl_xor(v, o, 64);
    acc[d] = v;
  }
  if (lane == 0) {
#pragma unroll
    for (int d = 0; d < DH; d++) ored[wid][d] = acc[d] * inv;
  }
  __syncthreads();
  if (lane < DH) O[(size_t)qi * DIM + h * DH + lane] = ored[wid][lane];
}

// ---------------- Final classifier GEMM: [4096,256]@[256,16]+b --------------
__global__ __launch_bounds__(256) void gemm_out_kernel(
    const float* __restrict__ Hm, const float* __restrict__ B,
    const float* __restrict__ bias, float* __restrict__ C) {
  __shared__ float Bs[256 * 16];
  int tid = threadIdx.x;
#pragma unroll
  for (int i = 0; i < 16; i++) Bs[i * 256 + tid] = B[i * 256 + tid];
  __syncthreads();
  int row = blockIdx.x * 16 + (tid >> 4);
  int col = tid & 15;
  const float* hp = Hm + (size_t)row * 256;
  float sacc = bias[col];
#pragma unroll 8
  for (int k = 0; k < 256; k++) sacc = fmaf(hp[k], Bs[k * 16 + col], sacc);
  C[(size_t)row * NCLS + col] = sacc;
}

extern "C" void kernel_launch(void* const* d_in, const int* in_sizes, int n_in,
                              void* d_out, int out_size, void* d_ws,
                              size_t ws_size, hipStream_t stream) {
  const float* nf = (const float*)d_in[0];
  const float* ef = (const float*)d_in[1];
  const int* ei = (const int*)d_in[2];
  const float* w_rn = (const float*)d_in[3];
  const float* b_rn = (const float*)d_in[4];
  const float* w_re = (const float*)d_in[5];
  const float* b_re = (const float*)d_in[6];
  const float* wq_n = (const float*)d_in[7];
  const float* bq_n = (const float*)d_in[8];
  const float* wk_n = (const float*)d_in[9];
  const float* bk_n = (const float*)d_in[10];
  const float* wv_n = (const float*)d_in[11];
  const float* bv_n = (const float*)d_in[12];
  const float* wo_n = (const float*)d_in[13];
  const float* bo_n = (const float*)d_in[14];
  const float* wq_e = (const float*)d_in[15];
  const float* bq_e = (const float*)d_in[16];
  const float* wk_e = (const float*)d_in[17];
  const float* bk_e = (const float*)d_in[18];
  const float* wv_e = (const float*)d_in[19];
  const float* bv_e = (const float*)d_in[20];
  const float* wo_e = (const float*)d_in[21];
  const float* bo_e = (const float*)d_in[22];
  const float* w_ne = (const float*)d_in[23];
  const float* b_ne = (const float*)d_in[24];
  const float* w_c1 = (const float*)d_in[25];
  const float* b_c1 = (const float*)d_in[26];
  const float* w_c2 = (const float*)d_in[27];
  const float* b_c2 = (const float*)d_in[28];

  const int* src = ei;
  const int* dst = ei + N_EDGES;

  float* ws = (float*)d_ws;
  size_t o = 0;
  float* ns = ws + o;   o += 2048;
  float* es = ws + o;   o += 4096;
  float* thr = ws + o;  o += 64;
  int* nmask = (int*)(ws + o); o += 2048;
  float* xn = ws + o;   o += (size_t)N_NODES * DIM;
  float* xe = ws + o;   o += (size_t)N_EDGES * DIM;
  float* qn = ws + o;   o += (size_t)N_NODES * DIM;
  float* kn = ws + o;   o += (size_t)N_NODES * DIM;
  float* vn = ws + o;   o += (size_t)N_NODES * DIM;
  float* qe = ws + o;   o += (size_t)N_EDGES * DIM;
  float* ke = ws + o;   o += (size_t)N_EDGES * DIM;
  float* ve = ws + o;   o += (size_t)N_EDGES * DIM;
  float* aon = ws + o;  o += (size_t)N_NODES * DIM;
  float* aoe = ws + o;  o += (size_t)N_EDGES * DIM;
  float* pn = ws + o;   o += (size_t)N_NODES * DIM;
  float* pe = ws + o;   o += (size_t)N_EDGES * DIM;
  float* ue = ws + o;   o += (size_t)N_EDGES * DIM;
  float* hb = ws + o;   o += (size_t)N_EDGES * 2 * DIM;

  // 1. router: scores + gated features
  router_kernel<<<dim3((N_NODES + N_EDGES) / 4), 256, 0, stream>>>(
      nf, ef, w_rn, b_rn, w_re, b_re, ns, es, xn, xe);
  // 2. top-k threshold + node mask
  topk_mask_kernel<<<1, 1024, 0, stream>>>(ns, nmask, thr);
  // 3-8. QKV projections
  gemm_kernel<0><<<dim3(32, 2), 256, 0, stream>>>(xn, wq_n, bq_n, qn, N_NODES, DIM, DIM);
  gemm_kernel<0><<<dim3(32, 2), 256, 0, stream>>>(xn, wk_n, bk_n, kn, N_NODES, DIM, DIM);
  gemm_kernel<0><<<dim3(32, 2), 256, 0, stream>>>(xn, wv_n, bv_n, vn, N_NODES, DIM, DIM);
  gemm_kernel<0><<<dim3(64, 2), 256, 0, stream>>>(xe, wq_e, bq_e, qe, N_EDGES, DIM, DIM);
  gemm_kernel<0><<<dim3(64, 2), 256, 0, stream>>>(xe, wk_e, bk_e, ke, N_EDGES, DIM, DIM);
  gemm_kernel<0><<<dim3(64, 2), 256, 0, stream>>>(xe, wv_e, bv_e, ve, N_EDGES, DIM, DIM);
  // 9-10. attention
  attn_node_kernel<<<dim3(N_NODES / 4, HEADS), 256, 0, stream>>>(qn, kn, vn, nmask, aon);
  attn_edge_kernel<<<dim3(N_EDGES / 4, HEADS), 256, 0, stream>>>(qe, ke, ve, src, dst, aoe);
  // 11-12. output projections
  gemm_kernel<0><<<dim3(32, 2), 256, 0, stream>>>(aon, wo_n, bo_n, pn, N_NODES, DIM, DIM);
  gemm_kernel<0><<<dim3(64, 2), 256, 0, stream>>>(aoe, wo_e, bo_e, pe, N_EDGES, DIM, DIM);
  // 13. updated_edges = pe + (pn[src]+pn[dst]) @ w_ne + b_ne
  gemm_msg_kernel<<<dim3(64, 2), 256, 0, stream>>>(pn, src, dst, w_ne, b_ne, pe, ue);
  // 14. h = gelu(ue @ w_c1 + b_c1)
  gemm_kernel<1><<<dim3(64, 4), 256, 0, stream>>>(ue, w_c1, b_c1, hb, N_EDGES, 2 * DIM, DIM);
  // 15. out = h @ w_c2 + b_c2
  gemm_out_kernel<<<dim3(N_EDGES / 16), 256, 0, stream>>>(hb, w_c2, b_c2, (float*)d_out);
}

// Round 3
// 149.082 us; speedup vs baseline: 4.8763x; 4.8763x over previous
//
#include <hip/hip_runtime.h>
#include <math.h>

#define N_NODES 2048
#define N_EDGES 4096
#define DIM 128
#define HEADS 4
#define DH 32
#define NCLS 16
#define TOPK 1024
#define NBR_CAP 64
#define SCALE 0.17677669529663687f  // 1/sqrt(32)

__device__ __forceinline__ float wave_reduce_sum(float v) {
#pragma unroll
  for (int o = 32; o > 0; o >>= 1) v += __shfl_xor(v, o, 64);
  return v;
}

// ---------------- Router: scores + gated features (nodes then edges) --------
__global__ __launch_bounds__(256) void router_kernel(
    const float* __restrict__ nf, const float* __restrict__ ef,
    const float* __restrict__ w_rn, const float* __restrict__ b_rn,
    const float* __restrict__ w_re, const float* __restrict__ b_re,
    float* __restrict__ ns, float* __restrict__ xn, float* __restrict__ xe) {
  int wid = threadIdx.x >> 6, lane = threadIdx.x & 63;
  int row = blockIdx.x * 4 + wid;
  const float* feat;
  const float* w;
  float b;
  float* scp;
  float* xp;
  if (row < N_NODES) {
    feat = nf + (size_t)row * DIM;
    w = w_rn; b = b_rn[0];
    scp = ns + row; xp = xn + (size_t)row * DIM;
  } else {
    int r = row - N_NODES;
    feat = ef + (size_t)r * DIM;
    w = w_re; b = b_re[0];
    scp = nullptr; xp = xe + (size_t)r * DIM;
  }
  float f0 = feat[lane], f1 = feat[lane + 64];
  float d = f0 * w[lane] + f1 * w[lane + 64];
  d = wave_reduce_sum(d);
  float sc = 1.0f / (1.0f + __expf(-(d + b)));
  xp[lane] = f0 * sc;
  xp[lane + 64] = f1 * sc;
  if (lane == 0 && scp) *scp = sc;
}

// ---------------- Top-k threshold + compacted kept-key list -----------------
// kth largest = max{v : count(s >= v) >= k}; binary search over float bit
// patterns (sigmoid scores in (0,1) -> positive -> bit order == value order).
// 64-bit midpoint (u32 version overflowed and hung in round 1).
__global__ __launch_bounds__(1024) void topk_kernel(
    const float* __restrict__ ns, int* __restrict__ kidx,
    int* __restrict__ nkept) {
  __shared__ int cnt;
  __shared__ int wcnt;
  int tid = threadIdx.x;
  unsigned b0 = __float_as_uint(ns[tid]);
  unsigned b1 = __float_as_uint(ns[tid + 1024]);
  unsigned lo = 0u, hi = 0x3F800000u;  // scores < 1.0f
  while (lo < hi) {
    unsigned mid = (unsigned)(((unsigned long long)lo + hi + 1ull) >> 1);
    if (tid == 0) cnt = 0;
    __syncthreads();
    int c = (b0 >= mid) + (b1 >= mid);
#pragma unroll
    for (int o = 1; o < 64; o <<= 1) c += __shfl_xor(c, o, 64);
    if ((tid & 63) == 0) atomicAdd(&cnt, c);
    __syncthreads();
    int total = cnt;
    __syncthreads();
    if (total >= TOPK) lo = mid; else hi = mid - 1;
  }
  if (tid == 0) wcnt = 0;
  __syncthreads();
  // compact kept key indices (order irrelevant: softmax is permutation-inv)
  if (b0 >= lo) kidx[atomicAdd(&wcnt, 1)] = tid;
  if (b1 >= lo) kidx[atomicAdd(&wcnt, 1)] = tid + 1024;
  __syncthreads();
  if (tid == 0) nkept[0] = wcnt;
}

// ---------------- Line-graph adjacency -> fixed-cap neighbor lists ----------
// deg ~ Binomial(4096, ~2e-3) ~= 9 incl. self; P(deg > 64) ~ 1e-30.
__global__ __launch_bounds__(256) void build_nbr_kernel(
    const int* __restrict__ src, const int* __restrict__ dst,
    int* __restrict__ nbr, int* __restrict__ deg) {
  __shared__ int cnt[4];
  int w = threadIdx.x >> 6, lane = threadIdx.x & 63;
  int qi = blockIdx.x * 4 + w;
  if (lane == 0) cnt[w] = 0;
  __syncthreads();
  int sq = src[qi], dq = dst[qi];
  for (int j = lane; j < N_EDGES; j += 64) {
    int sj = src[j], dj = dst[j];
    if (sj == sq || sj == dq || dj == sq || dj == dq) {
      int pos = atomicAdd(&cnt[w], 1);
      if (pos < NBR_CAP) nbr[(size_t)qi * NBR_CAP + pos] = j;
    }
  }
  __syncthreads();
  if (lane == 0) deg[qi] = min(cnt[w], NBR_CAP);
}

// ---------------- Shared 64x64 f32 GEMM tile body (K=128, float4 LDS) -------
__device__ __forceinline__ void gemm_body(
    float (&As)[16][68], float (&Bs)[16][68],
    const float* __restrict__ A, const float* __restrict__ B,
    int bm, int bn, int N, float4 (&acc)[4], int tid) {
  int tm = (tid >> 4) * 4, tn = (tid & 15) * 4;
  for (int k0 = 0; k0 < DIM; k0 += 16) {
#pragma unroll
    for (int i = 0; i < 4; i++) {
      int e = i * 256 + tid;
      int r = e >> 4, kk = e & 15;
      As[kk][r] = A[(size_t)(bm + r) * DIM + k0 + kk];
      int kb = e >> 6, c = e & 63;
      Bs[kb][c] = B[(size_t)(k0 + kb) * N + bn + c];
    }
    __syncthreads();
#pragma unroll
    for (int kk = 0; kk < 16; kk++) {
      float4 a = *(const float4*)&As[kk][tm];
      float4 b = *(const float4*)&Bs[kk][tn];
      acc[0].x = fmaf(a.x, b.x, acc[0].x); acc[0].y = fmaf(a.x, b.y, acc[0].y);
      acc[0].z = fmaf(a.x, b.z, acc[0].z); acc[0].w = fmaf(a.x, b.w, acc[0].w);
      acc[1].x = fmaf(a.y, b.x, acc[1].x); acc[1].y = fmaf(a.y, b.y, acc[1].y);
      acc[1].z = fmaf(a.y, b.z, acc[1].z); acc[1].w = fmaf(a.y, b.w, acc[1].w);
      acc[2].x = fmaf(a.z, b.x, acc[2].x); acc[2].y = fmaf(a.z, b.y, acc[2].y);
      acc[2].z = fmaf(a.z, b.z, acc[2].z); acc[2].w = fmaf(a.z, b.w, acc[2].w);
      acc[3].x = fmaf(a.w, b.x, acc[3].x); acc[3].y = fmaf(a.w, b.y, acc[3].y);
      acc[3].z = fmaf(a.w, b.z, acc[3].z); acc[3].w = fmaf(a.w, b.w, acc[3].w);
    }
    __syncthreads();
  }
}

// ---------------- Fused QKV projections: 6 GEMMs in one launch --------------
// grid (96, 6): x<32 -> node m-blocks, x>=32 -> edge; y = mat*2 + ntile.
__global__ __launch_bounds__(256) void gemm_qkv_kernel(
    const float* __restrict__ xn, const float* __restrict__ xe,
    const float* __restrict__ wq_n, const float* __restrict__ wk_n,
    const float* __restrict__ wv_n, const float* __restrict__ wq_e,
    const float* __restrict__ wk_e, const float* __restrict__ wv_e,
    const float* __restrict__ bq_n, const float* __restrict__ bk_n,
    const float* __restrict__ bv_n, const float* __restrict__ bq_e,
    const float* __restrict__ bk_e, const float* __restrict__ bv_e,
    float* __restrict__ qn, float* __restrict__ kn, float* __restrict__ vn,
    float* __restrict__ qe, float* __restrict__ ke, float* __restrict__ ve) {
  __shared__ float As[16][68];
  __shared__ float Bs[16][68];
  int bx = blockIdx.x;
  int mat = blockIdx.y >> 1;
  int bn = (blockIdx.y & 1) * 64;
  bool edge = bx >= 32;
  int bm = edge ? (bx - 32) * 64 : bx * 64;
  const float* A = edge ? xe : xn;
  const float* W;
  const float* bias;
  float* C;
  if (!edge) {
    if (mat == 0) { W = wq_n; bias = bq_n; C = qn; }
    else if (mat == 1) { W = wk_n; bias = bk_n; C = kn; }
    else { W = wv_n; bias = bv_n; C = vn; }
  } else {
    if (mat == 0) { W = wq_e; bias = bq_e; C = qe; }
    else if (mat == 1) { W = wk_e; bias = bk_e; C = ke; }
    else { W = wv_e; bias = bv_e; C = ve; }
  }
  float4 acc[4] = {{0,0,0,0},{0,0,0,0},{0,0,0,0},{0,0,0,0}};
  int tid = threadIdx.x;
  gemm_body(As, Bs, A, W, bm, bn, DIM, acc, tid);
  int tm = (tid >> 4) * 4, tn = (tid & 15) * 4;
  float4 b4 = *(const float4*)&bias[bn + tn];
#pragma unroll
  for (int i = 0; i < 4; i++) {
    float4 r;
    r.x = acc[i].x + b4.x; r.y = acc[i].y + b4.y;
    r.z = acc[i].z + b4.z; r.w = acc[i].w + b4.w;
    *(float4*)&C[(size_t)(bm + tm + i) * DIM + bn + tn] = r;
  }
}

// ---------------- Fused output projections (node + edge) --------------------
__global__ __launch_bounds__(256) void gemm_oproj_kernel(
    const float* __restrict__ aon, const float* __restrict__ aoe,
    const float* __restrict__ wo_n, const float* __restrict__ wo_e,
    const float* __restrict__ bo_n, const float* __restrict__ bo_e,
    float* __restrict__ pn, float* __restrict__ pe) {
  __shared__ float As[16][68];
  __shared__ float Bs[16][68];
  int bx = blockIdx.x;
  int bn = blockIdx.y * 64;
  bool edge = bx >= 32;
  int bm = edge ? (bx - 32) * 64 : bx * 64;
  const float* A = edge ? aoe : aon;
  const float* W = edge ? wo_e : wo_n;
  const float* bias = edge ? bo_e : bo_n;
  float* C = edge ? pe : pn;
  float4 acc[4] = {{0,0,0,0},{0,0,0,0},{0,0,0,0},{0,0,0,0}};
  int tid = threadIdx.x;
  gemm_body(As, Bs, A, W, bm, bn, DIM, acc, tid);
  int tm = (tid >> 4) * 4, tn = (tid & 15) * 4;
  float4 b4 = *(const float4*)&bias[bn + tn];
#pragma unroll
  for (int i = 0; i < 4; i++) {
    float4 r;
    r.x = acc[i].x + b4.x; r.y = acc[i].y + b4.y;
    r.z = acc[i].z + b4.z; r.w = acc[i].w + b4.w;
    *(float4*)&C[(size_t)(bm + tm + i) * DIM + bn + tn] = r;
  }
}

// ---------------- Gather GEMM: C = (NO[src]+NO[dst])@B + bias + EO ----------
__global__ __launch_bounds__(256) void gemm_msg_kernel(
    const float* __restrict__ NO, const int* __restrict__ src,
    const int* __restrict__ dst, const float* __restrict__ B,
    const float* __restrict__ bias, const float* __restrict__ EO,
    float* __restrict__ C) {
  __shared__ float As[16][68];
  __shared__ float Bs[16][68];
  int bm = blockIdx.x * 64, bn = blockIdx.y * 64;
  int tid = threadIdx.x;
  int tm = (tid >> 4) * 4, tn = (tid & 15) * 4;
  float4 acc[4] = {{0,0,0,0},{0,0,0,0},{0,0,0,0},{0,0,0,0}};
  for (int k0 = 0; k0 < DIM; k0 += 16) {
#pragma unroll
    for (int i = 0; i < 4; i++) {
      int e = i * 256 + tid;
      int r = e >> 4, kk = e & 15;
      int row = bm + r;
      int s0 = src[row], d0 = dst[row];
      As[kk][r] = NO[(size_t)s0 * DIM + k0 + kk] + NO[(size_t)d0 * DIM + k0 + kk];
      int kb = e >> 6, c = e & 63;
      Bs[kb][c] = B[(size_t)(k0 + kb) * DIM + bn + c];
    }
    __syncthreads();
#pragma unroll
    for (int kk = 0; kk < 16; kk++) {
      float4 a = *(const float4*)&As[kk][tm];
      float4 b = *(const float4*)&Bs[kk][tn];
      acc[0].x = fmaf(a.x, b.x, acc[0].x); acc[0].y = fmaf(a.x, b.y, acc[0].y);
      acc[0].z = fmaf(a.x, b.z, acc[0].z); acc[0].w = fmaf(a.x, b.w, acc[0].w);
      acc[1].x = fmaf(a.y, b.x, acc[1].x); acc[1].y = fmaf(a.y, b.y, acc[1].y);
      acc[1].z = fmaf(a.y, b.z, acc[1].z); acc[1].w = fmaf(a.y, b.w, acc[1].w);
      acc[2].x = fmaf(a.z, b.x, acc[2].x); acc[2].y = fmaf(a.z, b.y, acc[2].y);
      acc[2].z = fmaf(a.z, b.z, acc[2].z); acc[2].w = fmaf(a.z, b.w, acc[2].w);
      acc[3].x = fmaf(a.w, b.x, acc[3].x); acc[3].y = fmaf(a.w, b.y, acc[3].y);
      acc[3].z = fmaf(a.w, b.z, acc[3].z); acc[3].w = fmaf(a.w, b.w, acc[3].w);
    }
    __syncthreads();
  }
  float4 b4 = *(const float4*)&bias[bn + tn];
#pragma unroll
  for (int i = 0; i < 4; i++) {
    size_t idx = (size_t)(bm + tm + i) * DIM + bn + tn;
    float4 e4 = *(const float4*)&EO[idx];
    float4 r;
    r.x = acc[i].x + b4.x + e4.x; r.y = acc[i].y + b4.y + e4.y;
    r.z = acc[i].z + b4.z + e4.z; r.w = acc[i].w + b4.w + e4.w;
    *(float4*)&C[idx] = r;
  }
}

// ---------------- GELU GEMM: h = gelu(ue @ w_c1 + b), N=256 -----------------
__global__ __launch_bounds__(256) void gemm_gelu_kernel(
    const float* __restrict__ A, const float* __restrict__ B,
    const float* __restrict__ bias, float* __restrict__ C) {
  __shared__ float As[16][68];
  __shared__ float Bs[16][68];
  int bm = blockIdx.x * 64, bn = blockIdx.y * 64;
  int tid = threadIdx.x;
  float4 acc[4] = {{0,0,0,0},{0,0,0,0},{0,0,0,0},{0,0,0,0}};
  gemm_body(As, Bs, A, B, bm, bn, 256, acc, tid);
  int tm = (tid >> 4) * 4, tn = (tid & 15) * 4;
  float4 b4 = *(const float4*)&bias[bn + tn];
#pragma unroll
  for (int i = 0; i < 4; i++) {
    float vv[4] = {acc[i].x + b4.x, acc[i].y + b4.y, acc[i].z + b4.z,
                   acc[i].w + b4.w};
#pragma unroll
    for (int j = 0; j < 4; j++) {
      float v = vv[j];
      float u = 0.7978845608028654f * (v + 0.044715f * v * v * v);
      vv[j] = 0.5f * v * (1.0f + tanhf(u));
    }
    float4 r = {vv[0], vv[1], vv[2], vv[3]};
    *(float4*)&C[(size_t)(bm + tm + i) * 256 + bn + tn] = r;
  }
}

// ---------------- Node attention over compacted keys ------------------------
// Scores are tiny (|s| <= ~0.1): exp() cannot overflow, so skip the running
// max entirely (softmax is shift-invariant). Block = 16 queries x 16
// key-slices; keys staged once per block (16x less staging than round 2).
__global__ __launch_bounds__(256) void attn_node_kernel(
    const float* __restrict__ Q, const float* __restrict__ K,
    const float* __restrict__ V, const int* __restrict__ kidx,
    const int* __restrict__ nkeptp, float* __restrict__ O) {
  __shared__ float Ks[64][36];
  __shared__ float Vs[64][36];
  int h = blockIdx.y;
  int tid = threadIdx.x;
  int q = tid >> 4, e = tid & 15;
  int qi = blockIdx.x * 16 + q;
  int nkept = nkeptp[0];
  float4 qv[8];
  const float4* qp = (const float4*)(Q + (size_t)qi * DIM + h * DH);
#pragma unroll
  for (int i = 0; i < 8; i++) qv[i] = qp[i];
  float s = 0.f;
  float4 acc[8];
#pragma unroll
  for (int i = 0; i < 8; i++) acc[i] = make_float4(0.f, 0.f, 0.f, 0.f);

  for (int t0 = 0; t0 < nkept; t0 += 64) {
#pragma unroll
    for (int i = 0; i < 8; i++) {
      int e2 = i * 256 + tid;
      int r = e2 >> 5, d = e2 & 31;
      int row = t0 + r;
      int ki = (row < nkept) ? kidx[row] : kidx[0];
      Ks[r][d] = K[(size_t)ki * DIM + h * DH + d];
      Vs[r][d] = V[(size_t)ki * DIM + h * DH + d];
    }
    __syncthreads();
    int nk = nkept - t0;
    if (nk > 64) nk = 64;
#pragma unroll
    for (int j8 = 0; j8 < 4; j8++) {
      int j = j8 * 16 + e;
      if (j < nk) {
        const float4* kr = (const float4*)&Ks[j][0];
        const float4* vr = (const float4*)&Vs[j][0];
        float4 ps = make_float4(0.f, 0.f, 0.f, 0.f);
#pragma unroll
        for (int i = 0; i < 8; i++) {
          float4 kv = kr[i];
          ps.x = fmaf(qv[i].x, kv.x, ps.x);
          ps.y = fmaf(qv[i].y, kv.y, ps.y);
          ps.z = fmaf(qv[i].z, kv.z, ps.z);
          ps.w = fmaf(qv[i].w, kv.w, ps.w);
        }
        float p = __expf(((ps.x + ps.y) + (ps.z + ps.w)) * SCALE);
        s += p;
#pragma unroll
        for (int i = 0; i < 8; i++) {
          float4 vv = vr[i];
          acc[i].x = fmaf(p, vv.x, acc[i].x);
          acc[i].y = fmaf(p, vv.y, acc[i].y);
          acc[i].z = fmaf(p, vv.z, acc[i].z);
          acc[i].w = fmaf(p, vv.w, acc[i].w);
        }
      }
    }
    __syncthreads();
  }
  // reduce the 16 key-slices (lanes e = tid bits 0..3, within one wave)
#pragma unroll
  for (int o = 1; o <= 8; o <<= 1) {
    s += __shfl_xor(s, o, 64);
#pragma unroll
    for (int i = 0; i < 8; i++) {
      acc[i].x += __shfl_xor(acc[i].x, o, 64);
      acc[i].y += __shfl_xor(acc[i].y, o, 64);
      acc[i].z += __shfl_xor(acc[i].z, o, 64);
      acc[i].w += __shfl_xor(acc[i].w, o, 64);
    }
  }
  if (e == 0) {
    float inv = 1.0f / s;
    float4* op = (float4*)(O + (size_t)qi * DIM + h * DH);
#pragma unroll
    for (int i = 0; i < 8; i++) {
      float4 r;
      r.x = acc[i].x * inv; r.y = acc[i].y * inv;
      r.z = acc[i].z * inv; r.w = acc[i].w * inv;
      op[i] = r;
    }
  }
}

// ---------------- Edge attention over precomputed neighbor lists ------------
// Block = one query edge, 4 waves = 4 heads; lane = (nbr slot 0..15, dim
// quarter 0..3). deg ~ 9 so usually a single chunk. No max-subtraction
// (scores tiny), self-edge guarantees deg >= 1.
__global__ __launch_bounds__(256) void attn_edge_kernel(
    const float* __restrict__ Q, const float* __restrict__ Km,
    const float* __restrict__ V, const int* __restrict__ nbr,
    const int* __restrict__ deg, float* __restrict__ O) {
  int qi = blockIdx.x;
  int h = threadIdx.x >> 6;
  int lane = threadIdx.x & 63;
  int j16 = lane >> 2, g = lane & 3;
  int dg = deg[qi];
  const float4* qp = (const float4*)(Q + (size_t)qi * DIM + h * DH + g * 8);
  float4 q0 = qp[0], q1 = qp[1];
  float s = 0.f;
  float4 a0 = make_float4(0.f, 0.f, 0.f, 0.f);
  float4 a1 = make_float4(0.f, 0.f, 0.f, 0.f);
  for (int c0 = 0; c0 < dg; c0 += 16) {
    int j = c0 + j16;
    bool act = j < dg;
    int ei = act ? nbr[(size_t)qi * NBR_CAP + j] : 0;
    const float4* kp = (const float4*)(Km + (size_t)ei * DIM + h * DH + g * 8);
    float4 k0 = kp[0], k1 = kp[1];
    float pd = q0.x * k0.x + q0.y * k0.y + q0.z * k0.z + q0.w * k0.w +
               q1.x * k1.x + q1.y * k1.y + q1.z * k1.z + q1.w * k1.w;
    pd += __shfl_xor(pd, 1, 64);
    pd += __shfl_xor(pd, 2, 64);  // full 32-dot in all 4 lanes of the group
    float p = act ? __expf(pd * SCALE) : 0.f;
    s += p;
    const float4* vp = (const float4*)(V + (size_t)ei * DIM + h * DH + g * 8);
    float4 v0 = vp[0], v1 = vp[1];
    a0.x = fmaf(p, v0.x, a0.x); a0.y = fmaf(p, v0.y, a0.y);
    a0.z = fmaf(p, v0.z, a0.z); a0.w = fmaf(p, v0.w, a0.w);
    a1.x = fmaf(p, v1.x, a1.x); a1.y = fmaf(p, v1.y, a1.y);
    a1.z = fmaf(p, v1.z, a1.z); a1.w = fmaf(p, v1.w, a1.w);
  }
#pragma unroll
  for (int o = 4; o <= 32; o <<= 1) {
    s += __shfl_xor(s, o, 64);
    a0.x += __shfl_xor(a0.x, o, 64); a0.y += __shfl_xor(a0.y, o, 64);
    a0.z += __shfl_xor(a0.z, o, 64); a0.w += __shfl_xor(a0.w, o, 64);
    a1.x += __shfl_xor(a1.x, o, 64); a1.y += __shfl_xor(a1.y, o, 64);
    a1.z += __shfl_xor(a1.z, o, 64); a1.w += __shfl_xor(a1.w, o, 64);
  }
  if (j16 == 0) {
    float inv = 1.0f / s;
    float4* op = (float4*)(O + (size_t)qi * DIM + h * DH + g * 8);
    float4 r0 = {a0.x * inv, a0.y * inv, a0.z * inv, a0.w * inv};
    float4 r1 = {a1.x * inv, a1.y * inv, a1.z * inv, a1.w * inv};
    op[0] = r0;
    op[1] = r1;
  }
}

// ---------------- Final classifier GEMM: [4096,256]@[256,16]+b --------------
__global__ __launch_bounds__(256) void gemm_out_kernel(
    const float* __restrict__ Hm, const float* __restrict__ B,
    const float* __restrict__ bias, float* __restrict__ C) {
  __shared__ float Bs[256 * 16];
  int tid = threadIdx.x;
#pragma unroll
  for (int i = 0; i < 16; i++) Bs[i * 256 + tid] = B[i * 256 + tid];
  __syncthreads();
  int row = blockIdx.x * 16 + (tid >> 4);
  int col = tid & 15;
  const float* hp = Hm + (size_t)row * 256;
  float sacc = bias[col];
#pragma unroll 8
  for (int k = 0; k < 256; k++) sacc = fmaf(hp[k], Bs[k * 16 + col], sacc);
  C[(size_t)row * NCLS + col] = sacc;
}

extern "C" void kernel_launch(void* const* d_in, const int* in_sizes, int n_in,
                              void* d_out, int out_size, void* d_ws,
                              size_t ws_size, hipStream_t stream) {
  const float* nf = (const float*)d_in[0];
  const float* ef = (const float*)d_in[1];
  const int* ei = (const int*)d_in[2];
  const float* w_rn = (const float*)d_in[3];
  const float* b_rn = (const float*)d_in[4];
  const float* w_re = (const float*)d_in[5];
  const float* b_re = (const float*)d_in[6];
  const float* wq_n = (const float*)d_in[7];
  const float* bq_n = (const float*)d_in[8];
  const float* wk_n = (const float*)d_in[9];
  const float* bk_n = (const float*)d_in[10];
  const float* wv_n = (const float*)d_in[11];
  const float* bv_n = (const float*)d_in[12];
  const float* wo_n = (const float*)d_in[13];
  const float* bo_n = (const float*)d_in[14];
  const float* wq_e = (const float*)d_in[15];
  const float* bq_e = (const float*)d_in[16];
  const float* wk_e = (const float*)d_in[17];
  const float* bk_e = (const float*)d_in[18];
  const float* wv_e = (const float*)d_in[19];
  const float* bv_e = (const float*)d_in[20];
  const float* wo_e = (const float*)d_in[21];
  const float* bo_e = (const float*)d_in[22];
  const float* w_ne = (const float*)d_in[23];
  const float* b_ne = (const float*)d_in[24];
  const float* w_c1 = (const float*)d_in[25];
  const float* b_c1 = (const float*)d_in[26];
  const float* w_c2 = (const float*)d_in[27];
  const float* b_c2 = (const float*)d_in[28];

  const int* src = ei;
  const int* dst = ei + N_EDGES;

  float* ws = (float*)d_ws;
  size_t o = 0;
  float* ns = ws + o;   o += 2048;
  int* kidx = (int*)(ws + o); o += 2048;
  int* nkept = (int*)(ws + o); o += 64;
  int* nbr = (int*)(ws + o); o += (size_t)N_EDGES * NBR_CAP;
  int* degp = (int*)(ws + o); o += N_EDGES;
  float* xn = ws + o;   o += (size_t)N_NODES * DIM;
  float* xe = ws + o;   o += (size_t)N_EDGES * DIM;
  float* qn = ws + o;   o += (size_t)N_NODES * DIM;
  float* kn = ws + o;   o += (size_t)N_NODES * DIM;
  float* vn = ws + o;   o += (size_t)N_NODES * DIM;
  float* qe = ws + o;   o += (size_t)N_EDGES * DIM;
  float* ke = ws + o;   o += (size_t)N_EDGES * DIM;
  float* ve = ws + o;   o += (size_t)N_EDGES * DIM;
  float* aon = ws + o;  o += (size_t)N_NODES * DIM;
  float* aoe = ws + o;  o += (size_t)N_EDGES * DIM;
  float* pn = ws + o;   o += (size_t)N_NODES * DIM;
  float* pe = ws + o;   o += (size_t)N_EDGES * DIM;
  float* ue = ws + o;   o += (size_t)N_EDGES * DIM;
  float* hb = ws + o;   o += (size_t)N_EDGES * 2 * DIM;

  // 1. router: scores + gated features
  router_kernel<<<dim3((N_NODES + N_EDGES) / 4), 256, 0, stream>>>(
      nf, ef, w_rn, b_rn, w_re, b_re, ns, xn, xe);
  // 2. top-k threshold + compacted kept-key list
  topk_kernel<<<1, 1024, 0, stream>>>(ns, kidx, nkept);
  // 3. line-graph neighbor lists
  build_nbr_kernel<<<dim3(N_EDGES / 4), 256, 0, stream>>>(src, dst, nbr, degp);
  // 4. all six QKV projections, one launch
  gemm_qkv_kernel<<<dim3(96, 6), 256, 0, stream>>>(
      xn, xe, wq_n, wk_n, wv_n, wq_e, wk_e, wv_e,
      bq_n, bk_n, bv_n, bq_e, bk_e, bv_e, qn, kn, vn, qe, ke, ve);
  // 5-6. attention
  attn_node_kernel<<<dim3(N_NODES / 16, HEADS), 256, 0, stream>>>(
      qn, kn, vn, kidx, nkept, aon);
  attn_edge_kernel<<<dim3(N_EDGES), 256, 0, stream>>>(
      qe, ke, ve, nbr, degp, aoe);
  // 7. both output projections, one launch
  gemm_oproj_kernel<<<dim3(96, 2), 256, 0, stream>>>(
      aon, aoe, wo_n, wo_e, bo_n, bo_e, pn, pe);
  // 8. updated_edges = pe + (pn[src]+pn[dst]) @ w_ne + b_ne
  gemm_msg_kernel<<<dim3(64, 2), 256, 0, stream>>>(pn, src, dst, w_ne, b_ne,
                                                   pe, ue);
  // 9. h = gelu(ue @ w_c1 + b_c1)
  gemm_gelu_kernel<<<dim3(64, 4), 256, 0, stream>>>(ue, w_c1, b_c1, hb);
  // 10. out = h @ w_c2 + b_c2
  gemm_out_kernel<<<dim3(N_EDGES / 16), 256, 0, stream>>>(hb, w_c2, b_c2,
                                                          (float*)d_out);
}

// Round 4
// 140.584 us; speedup vs baseline: 5.1711x; 1.0604x over previous
//
#include <hip/hip_runtime.h>
#include <math.h>

#define N_NODES 2048
#define N_EDGES 4096
#define DIM 128
#define HEADS 4
#define DH 32
#define NCLS 16
#define TOPK 1024
#define NBR_CAP 64
#define NSPLIT 4
#define SCALE 0.17677669529663687f  // 1/sqrt(32)

__device__ __forceinline__ float wave_reduce_sum(float v) {
#pragma unroll
  for (int o = 32; o > 0; o >>= 1) v += __shfl_xor(v, o, 64);
  return v;
}

// ---------------- Scores only (gating folded into QKV GEMM) -----------------
__global__ __launch_bounds__(256) void score_kernel(
    const float* __restrict__ nf, const float* __restrict__ ef,
    const float* __restrict__ w_rn, const float* __restrict__ b_rn,
    const float* __restrict__ w_re, const float* __restrict__ b_re,
    float* __restrict__ ns, float* __restrict__ es) {
  int wid = threadIdx.x >> 6, lane = threadIdx.x & 63;
  int row = blockIdx.x * 4 + wid;
  const float* feat;
  const float* w;
  float b;
  float* scp;
  if (row < N_NODES) {
    feat = nf + (size_t)row * DIM;
    w = w_rn; b = b_rn[0];
    scp = ns + row;
  } else {
    int r = row - N_NODES;
    feat = ef + (size_t)r * DIM;
    w = w_re; b = b_re[0];
    scp = es + r;
  }
  float d = feat[lane] * w[lane] + feat[lane + 64] * w[lane + 64];
  d = wave_reduce_sum(d);
  if (lane == 0) *scp = 1.0f / (1.0f + __expf(-(d + b)));
}

// ---------------- Top-k: single-wave binary search + block compact ----------
// kth largest = max{v : count(s >= v) >= k}. Wave 0 holds all 2048 score bit
// patterns in registers (32/lane); the ~30 dependent search rounds use only
// wave shuffles (no block syncs). Sigmoid scores in (0,1) -> positive floats
// -> bit order == value order. 64-bit midpoint (u32 overflow hung round 1).
__global__ __launch_bounds__(256) void topk_kernel(
    const float* __restrict__ ns, int* __restrict__ kidx,
    int* __restrict__ nkept) {
  __shared__ unsigned sh_lo;
  __shared__ int wcnt;
  int tid = threadIdx.x;
  if (tid == 0) wcnt = 0;
  if (tid < 64) {
    unsigned bv[32];
#pragma unroll
    for (int i = 0; i < 32; i++)
      bv[i] = __float_as_uint(ns[tid * 32 + i]);
    unsigned lo = 0u, hi = 0x3F800000u;  // scores < 1.0f
    while (lo < hi) {
      unsigned mid = (unsigned)(((unsigned long long)lo + hi + 1ull) >> 1);
      int c = 0;
#pragma unroll
      for (int i = 0; i < 32; i++) c += (bv[i] >= mid);
#pragma unroll
      for (int o = 1; o < 64; o <<= 1) c += __shfl_xor(c, o, 64);
      if (c >= TOPK) lo = mid; else hi = mid - 1;
    }
    if (tid == 0) sh_lo = lo;
  }
  __syncthreads();
  unsigned lo = sh_lo;
#pragma unroll
  for (int i = 0; i < 8; i++) {
    int idx = tid * 8 + i;
    if (__float_as_uint(ns[idx]) >= lo) kidx[atomicAdd(&wcnt, 1)] = idx;
  }
  __syncthreads();
  if (tid == 0) nkept[0] = wcnt;
}

// ---------------- Line-graph adjacency -> fixed-cap neighbor lists ----------
// 16 queries/block; src/dst staged once in LDS (32 KB) so the 16 waves scan
// LDS instead of 16x-redundant L2 reads. deg ~ 9; P(deg > 64) ~ 1e-30.
__global__ __launch_bounds__(1024) void build_nbr_kernel(
    const int* __restrict__ src, const int* __restrict__ dst,
    int* __restrict__ nbr, int* __restrict__ deg) {
  __shared__ int sL[N_EDGES];
  __shared__ int dL[N_EDGES];
  __shared__ int cnt[16];
  int tid = threadIdx.x;
  int w = tid >> 6, lane = tid & 63;
#pragma unroll
  for (int i = 0; i < 4; i++) {
    int j = i * 1024 + tid;
    sL[j] = src[j];
    dL[j] = dst[j];
  }
  if (lane == 0) cnt[w] = 0;
  __syncthreads();
  int qi = blockIdx.x * 16 + w;
  int sq = sL[qi], dq = dL[qi];
  for (int j = lane; j < N_EDGES; j += 64) {
    int sj = sL[j], dj = dL[j];
    if (sj == sq || sj == dq || dj == sq || dj == dq) {
      int pos = atomicAdd(&cnt[w], 1);
      if (pos < NBR_CAP) nbr[(size_t)qi * NBR_CAP + pos] = j;
    }
  }
  __syncthreads();
  if (lane == 0) deg[qi] = min(cnt[w], NBR_CAP);
}

// ---------------- Fused QKV projections with router gating -----------------
// A-row gated by score on LDS-stage: As = A[row] * score[row]. grid (96, 6).
__global__ __launch_bounds__(256) void gemm_qkv_kernel(
    const float* __restrict__ nf, const float* __restrict__ ef,
    const float* __restrict__ ns, const float* __restrict__ es,
    const float* __restrict__ wq_n, const float* __restrict__ wk_n,
    const float* __restrict__ wv_n, const float* __restrict__ wq_e,
    const float* __restrict__ wk_e, const float* __restrict__ wv_e,
    const float* __restrict__ bq_n, const float* __restrict__ bk_n,
    const float* __restrict__ bv_n, const float* __restrict__ bq_e,
    const float* __restrict__ bk_e, const float* __restrict__ bv_e,
    float* __restrict__ qn, float* __restrict__ kn, float* __restrict__ vn,
    float* __restrict__ qe, float* __restrict__ ke, float* __restrict__ ve) {
  __shared__ float As[16][68];
  __shared__ float Bs[16][68];
  __shared__ float ss[64];
  int bx = blockIdx.x;
  int mat = blockIdx.y >> 1;
  int bn = (blockIdx.y & 1) * 64;
  bool edge = bx >= 32;
  int bm = edge ? (bx - 32) * 64 : bx * 64;
  const float* A = edge ? ef : nf;
  const float* sc = edge ? es : ns;
  const float* W;
  const float* bias;
  float* C;
  if (!edge) {
    if (mat == 0) { W = wq_n; bias = bq_n; C = qn; }
    else if (mat == 1) { W = wk_n; bias = bk_n; C = kn; }
    else { W = wv_n; bias = bv_n; C = vn; }
  } else {
    if (mat == 0) { W = wq_e; bias = bq_e; C = qe; }
    else if (mat == 1) { W = wk_e; bias = bk_e; C = ke; }
    else { W = wv_e; bias = bv_e; C = ve; }
  }
  int tid = threadIdx.x;
  if (tid < 64) ss[tid] = sc[bm + tid];
  __syncthreads();
  int tm = (tid >> 4) * 4, tn = (tid & 15) * 4;
  float4 acc[4] = {{0,0,0,0},{0,0,0,0},{0,0,0,0},{0,0,0,0}};
  for (int k0 = 0; k0 < DIM; k0 += 16) {
#pragma unroll
    for (int i = 0; i < 4; i++) {
      int e = i * 256 + tid;
      int r = e >> 4, kk = e & 15;
      As[kk][r] = A[(size_t)(bm + r) * DIM + k0 + kk] * ss[r];
      int kb = e >> 6, c = e & 63;
      Bs[kb][c] = W[(size_t)(k0 + kb) * DIM + bn + c];
    }
    __syncthreads();
#pragma unroll
    for (int kk = 0; kk < 16; kk++) {
      float4 a = *(const float4*)&As[kk][tm];
      float4 b = *(const float4*)&Bs[kk][tn];
      acc[0].x = fmaf(a.x, b.x, acc[0].x); acc[0].y = fmaf(a.x, b.y, acc[0].y);
      acc[0].z = fmaf(a.x, b.z, acc[0].z); acc[0].w = fmaf(a.x, b.w, acc[0].w);
      acc[1].x = fmaf(a.y, b.x, acc[1].x); acc[1].y = fmaf(a.y, b.y, acc[1].y);
      acc[1].z = fmaf(a.y, b.z, acc[1].z); acc[1].w = fmaf(a.y, b.w, acc[1].w);
      acc[2].x = fmaf(a.z, b.x, acc[2].x); acc[2].y = fmaf(a.z, b.y, acc[2].y);
      acc[2].z = fmaf(a.z, b.z, acc[2].z); acc[2].w = fmaf(a.z, b.w, acc[2].w);
      acc[3].x = fmaf(a.w, b.x, acc[3].x); acc[3].y = fmaf(a.w, b.y, acc[3].y);
      acc[3].z = fmaf(a.w, b.z, acc[3].z); acc[3].w = fmaf(a.w, b.w, acc[3].w);
    }
    __syncthreads();
  }
  float4 b4 = *(const float4*)&bias[bn + tn];
#pragma unroll
  for (int i = 0; i < 4; i++) {
    float4 r;
    r.x = acc[i].x + b4.x; r.y = acc[i].y + b4.y;
    r.z = acc[i].z + b4.z; r.w = acc[i].w + b4.w;
    *(float4*)&C[(size_t)(bm + tm + i) * DIM + bn + tn] = r;
  }
}

// ---------------- Shared 64x64 f32 GEMM tile body (K=128, float4 LDS) -------
__device__ __forceinline__ void gemm_body(
    float (&As)[16][68], float (&Bs)[16][68],
    const float* __restrict__ A, const float* __restrict__ B,
    int bm, int bn, int N, float4 (&acc)[4], int tid) {
  int tm = (tid >> 4) * 4, tn = (tid & 15) * 4;
  for (int k0 = 0; k0 < DIM; k0 += 16) {
#pragma unroll
    for (int i = 0; i < 4; i++) {
      int e = i * 256 + tid;
      int r = e >> 4, kk = e & 15;
      As[kk][r] = A[(size_t)(bm + r) * DIM + k0 + kk];
      int kb = e >> 6, c = e & 63;
      Bs[kb][c] = B[(size_t)(k0 + kb) * N + bn + c];
    }
    __syncthreads();
#pragma unroll
    for (int kk = 0; kk < 16; kk++) {
      float4 a = *(const float4*)&As[kk][tm];
      float4 b = *(const float4*)&Bs[kk][tn];
      acc[0].x = fmaf(a.x, b.x, acc[0].x); acc[0].y = fmaf(a.x, b.y, acc[0].y);
      acc[0].z = fmaf(a.x, b.z, acc[0].z); acc[0].w = fmaf(a.x, b.w, acc[0].w);
      acc[1].x = fmaf(a.y, b.x, acc[1].x); acc[1].y = fmaf(a.y, b.y, acc[1].y);
      acc[1].z = fmaf(a.y, b.z, acc[1].z); acc[1].w = fmaf(a.y, b.w, acc[1].w);
      acc[2].x = fmaf(a.z, b.x, acc[2].x); acc[2].y = fmaf(a.z, b.y, acc[2].y);
      acc[2].z = fmaf(a.z, b.z, acc[2].z); acc[2].w = fmaf(a.z, b.w, acc[2].w);
      acc[3].x = fmaf(a.w, b.x, acc[3].x); acc[3].y = fmaf(a.w, b.y, acc[3].y);
      acc[3].z = fmaf(a.w, b.z, acc[3].z); acc[3].w = fmaf(a.w, b.w, acc[3].w);
    }
    __syncthreads();
  }
}

// ---------------- Fused output projections (node + edge) --------------------
__global__ __launch_bounds__(256) void gemm_oproj_kernel(
    const float* __restrict__ aon, const float* __restrict__ aoe,
    const float* __restrict__ wo_n, const float* __restrict__ wo_e,
    const float* __restrict__ bo_n, const float* __restrict__ bo_e,
    float* __restrict__ pn, float* __restrict__ pe) {
  __shared__ float As[16][68];
  __shared__ float Bs[16][68];
  int bx = blockIdx.x;
  int bn = blockIdx.y * 64;
  bool edge = bx >= 32;
  int bm = edge ? (bx - 32) * 64 : bx * 64;
  const float* A = edge ? aoe : aon;
  const float* W = edge ? wo_e : wo_n;
  const float* bias = edge ? bo_e : bo_n;
  float* C = edge ? pe : pn;
  float4 acc[4] = {{0,0,0,0},{0,0,0,0},{0,0,0,0},{0,0,0,0}};
  int tid = threadIdx.x;
  gemm_body(As, Bs, A, W, bm, bn, DIM, acc, tid);
  int tm = (tid >> 4) * 4, tn = (tid & 15) * 4;
  float4 b4 = *(const float4*)&bias[bn + tn];
#pragma unroll
  for (int i = 0; i < 4; i++) {
    float4 r;
    r.x = acc[i].x + b4.x; r.y = acc[i].y + b4.y;
    r.z = acc[i].z + b4.z; r.w = acc[i].w + b4.w;
    *(float4*)&C[(size_t)(bm + tm + i) * DIM + bn + tn] = r;
  }
}

// ---------------- Gather GEMM: C = (NO[src]+NO[dst])@B + bias + EO ----------
__global__ __launch_bounds__(256) void gemm_msg_kernel(
    const float* __restrict__ NO, const int* __restrict__ src,
    const int* __restrict__ dst, const float* __restrict__ B,
    const float* __restrict__ bias, const float* __restrict__ EO,
    float* __restrict__ C) {
  __shared__ float As[16][68];
  __shared__ float Bs[16][68];
  int bm = blockIdx.x * 64, bn = blockIdx.y * 64;
  int tid = threadIdx.x;
  int tm = (tid >> 4) * 4, tn = (tid & 15) * 4;
  float4 acc[4] = {{0,0,0,0},{0,0,0,0},{0,0,0,0},{0,0,0,0}};
  for (int k0 = 0; k0 < DIM; k0 += 16) {
#pragma unroll
    for (int i = 0; i < 4; i++) {
      int e = i * 256 + tid;
      int r = e >> 4, kk = e & 15;
      int row = bm + r;
      int s0 = src[row], d0 = dst[row];
      As[kk][r] = NO[(size_t)s0 * DIM + k0 + kk] + NO[(size_t)d0 * DIM + k0 + kk];
      int kb = e >> 6, c = e & 63;
      Bs[kb][c] = B[(size_t)(k0 + kb) * DIM + bn + c];
    }
    __syncthreads();
#pragma unroll
    for (int kk = 0; kk < 16; kk++) {
      float4 a = *(const float4*)&As[kk][tm];
      float4 b = *(const float4*)&Bs[kk][tn];
      acc[0].x = fmaf(a.x, b.x, acc[0].x); acc[0].y = fmaf(a.x, b.y, acc[0].y);
      acc[0].z = fmaf(a.x, b.z, acc[0].z); acc[0].w = fmaf(a.x, b.w, acc[0].w);
      acc[1].x = fmaf(a.y, b.x, acc[1].x); acc[1].y = fmaf(a.y, b.y, acc[1].y);
      acc[1].z = fmaf(a.y, b.z, acc[1].z); acc[1].w = fmaf(a.y, b.w, acc[1].w);
      acc[2].x = fmaf(a.z, b.x, acc[2].x); acc[2].y = fmaf(a.z, b.y, acc[2].y);
      acc[2].z = fmaf(a.z, b.z, acc[2].z); acc[2].w = fmaf(a.z, b.w, acc[2].w);
      acc[3].x = fmaf(a.w, b.x, acc[3].x); acc[3].y = fmaf(a.w, b.y, acc[3].y);
      acc[3].z = fmaf(a.w, b.z, acc[3].z); acc[3].w = fmaf(a.w, b.w, acc[3].w);
    }
    __syncthreads();
  }
  float4 b4 = *(const float4*)&bias[bn + tn];
#pragma unroll
  for (int i = 0; i < 4; i++) {
    size_t idx = (size_t)(bm + tm + i) * DIM + bn + tn;
    float4 e4 = *(const float4*)&EO[idx];
    float4 r;
    r.x = acc[i].x + b4.x + e4.x; r.y = acc[i].y + b4.y + e4.y;
    r.z = acc[i].z + b4.z + e4.z; r.w = acc[i].w + b4.w + e4.w;
    *(float4*)&C[idx] = r;
  }
}

// ---------------- GELU GEMM: h = gelu(ue @ w_c1 + b), N=256 -----------------
__global__ __launch_bounds__(256) void gemm_gelu_kernel(
    const float* __restrict__ A, const float* __restrict__ B,
    const float* __restrict__ bias, float* __restrict__ C) {
  __shared__ float As[16][68];
  __shared__ float Bs[16][68];
  int bm = blockIdx.x * 64, bn = blockIdx.y * 64;
  int tid = threadIdx.x;
  float4 acc[4] = {{0,0,0,0},{0,0,0,0},{0,0,0,0},{0,0,0,0}};
  gemm_body(As, Bs, A, B, bm, bn, 256, acc, tid);
  int tm = (tid >> 4) * 4, tn = (tid & 15) * 4;
  float4 b4 = *(const float4*)&bias[bn + tn];
#pragma unroll
  for (int i = 0; i < 4; i++) {
    float vv[4] = {acc[i].x + b4.x, acc[i].y + b4.y, acc[i].z + b4.z,
                   acc[i].w + b4.w};
#pragma unroll
    for (int j = 0; j < 4; j++) {
      float v = vv[j];
      float u = 0.7978845608028654f * (v + 0.044715f * v * v * v);
      vv[j] = 0.5f * v * (1.0f + tanhf(u));
    }
    float4 r = {vv[0], vv[1], vv[2], vv[3]};
    *(float4*)&C[(size_t)(bm + tm + i) * 256 + bn + tn] = r;
  }
}

// ---------------- Node attention, key-split x4 ------------------------------
// grid (128, H, NSPLIT). Block: 16 queries x 16 key-slices over its quarter
// of the kept keys; emits partial (acc[32], sum) per (q, h, split). Scores
// tiny (|s|<~0.1) -> exp cannot overflow -> no running max needed.
__global__ __launch_bounds__(256) void attn_node_kernel(
    const float* __restrict__ Q, const float* __restrict__ K,
    const float* __restrict__ V, const int* __restrict__ kidx,
    const int* __restrict__ nkeptp, float* __restrict__ pacc,
    float* __restrict__ ps) {
  __shared__ float Ks[64][36];
  __shared__ float Vs[64][36];
  int h = blockIdx.y;
  int sp = blockIdx.z;
  int tid = threadIdx.x;
  int q = tid >> 4, e = tid & 15;
  int qi = blockIdx.x * 16 + q;
  int nkept = nkeptp[0];
  int spl = (nkept + NSPLIT - 1) / NSPLIT;
  int start = sp * spl;
  int end = min(start + spl, nkept);
  float4 qv[8];
  const float4* qp = (const float4*)(Q + (size_t)qi * DIM + h * DH);
#pragma unroll
  for (int i = 0; i < 8; i++) qv[i] = qp[i];
  float s = 0.f;
  float4 acc[8];
#pragma unroll
  for (int i = 0; i < 8; i++) acc[i] = make_float4(0.f, 0.f, 0.f, 0.f);

  for (int t0 = start; t0 < end; t0 += 64) {
#pragma unroll
    for (int i = 0; i < 8; i++) {
      int e2 = i * 256 + tid;
      int r = e2 >> 5, d = e2 & 31;
      int row = t0 + r;
      int ki = (row < end) ? kidx[row] : kidx[0];
      Ks[r][d] = K[(size_t)ki * DIM + h * DH + d];
      Vs[r][d] = V[(size_t)ki * DIM + h * DH + d];
    }
    __syncthreads();
    int nk = end - t0;
    if (nk > 64) nk = 64;
#pragma unroll
    for (int j8 = 0; j8 < 4; j8++) {
      int j = j8 * 16 + e;
      if (j < nk) {
        const float4* kr = (const float4*)&Ks[j][0];
        const float4* vr = (const float4*)&Vs[j][0];
        float4 psum = make_float4(0.f, 0.f, 0.f, 0.f);
#pragma unroll
        for (int i = 0; i < 8; i++) {
          float4 kv = kr[i];
          psum.x = fmaf(qv[i].x, kv.x, psum.x);
          psum.y = fmaf(qv[i].y, kv.y, psum.y);
          psum.z = fmaf(qv[i].z, kv.z, psum.z);
          psum.w = fmaf(qv[i].w, kv.w, psum.w);
        }
        float p = __expf(((psum.x + psum.y) + (psum.z + psum.w)) * SCALE);
        s += p;
#pragma unroll
        for (int i = 0; i < 8; i++) {
          float4 vv = vr[i];
          acc[i].x = fmaf(p, vv.x, acc[i].x);
          acc[i].y = fmaf(p, vv.y, acc[i].y);
          acc[i].z = fmaf(p, vv.z, acc[i].z);
          acc[i].w = fmaf(p, vv.w, acc[i].w);
        }
      }
    }
    __syncthreads();
  }
  // reduce over the 16 key-slices (bits 0..3 of the lane id)
#pragma unroll
  for (int o = 1; o <= 8; o <<= 1) {
    s += __shfl_xor(s, o, 64);
#pragma unroll
    for (int i = 0; i < 8; i++) {
      acc[i].x += __shfl_xor(acc[i].x, o, 64);
      acc[i].y += __shfl_xor(acc[i].y, o, 64);
      acc[i].z += __shfl_xor(acc[i].z, o, 64);
      acc[i].w += __shfl_xor(acc[i].w, o, 64);
    }
  }
  if (e == 0) {
    size_t idx = ((size_t)qi * HEADS + h) * NSPLIT + sp;
    float4* pp = (float4*)(pacc + idx * 32);
#pragma unroll
    for (int i = 0; i < 8; i++) pp[i] = acc[i];
    ps[idx] = s;
  }
}

// ---------------- Node attention reduce: combine splits, normalize ----------
__global__ __launch_bounds__(256) void attn_node_reduce_kernel(
    const float* __restrict__ pacc, const float* __restrict__ ps,
    float* __restrict__ O) {
  int gid = blockIdx.x * 256 + threadIdx.x;
  int qh = gid >> 5, d = gid & 31;
  int q = qh >> 2, h = qh & 3;
  float ssum = 0.f, v = 0.f;
#pragma unroll
  for (int sp = 0; sp < NSPLIT; sp++) {
    size_t idx = (size_t)qh * NSPLIT + sp;
    ssum += ps[idx];
    v += pacc[idx * 32 + d];
  }
  O[(size_t)q * DIM + h * DH + d] = v / ssum;
}

// ---------------- Edge attention over neighbor lists ------------------------
// Block = 4 query edges; wave = head; lane = (q 2b | nbr-slot 2b | dim-qtr 2b).
__global__ __launch_bounds__(256) void attn_edge_kernel(
    const float* __restrict__ Q, const float* __restrict__ Km,
    const float* __restrict__ V, const int* __restrict__ nbr,
    const int* __restrict__ deg, float* __restrict__ O) {
  int h = threadIdx.x >> 6;
  int lane = threadIdx.x & 63;
  int ql = lane >> 4, j4 = (lane >> 2) & 3, g = lane & 3;
  int qi = blockIdx.x * 4 + ql;
  int dg = deg[qi];
  const float4* qp = (const float4*)(Q + (size_t)qi * DIM + h * DH + g * 8);
  float4 q0 = qp[0], q1 = qp[1];
  float s = 0.f;
  float4 a0 = make_float4(0.f, 0.f, 0.f, 0.f);
  float4 a1 = make_float4(0.f, 0.f, 0.f, 0.f);
  for (int c0 = 0; c0 < dg; c0 += 4) {
    int j = c0 + j4;
    bool act = j < dg;
    int ei = act ? nbr[(size_t)qi * NBR_CAP + j] : 0;
    const float4* kp = (const float4*)(Km + (size_t)ei * DIM + h * DH + g * 8);
    float4 k0 = kp[0], k1 = kp[1];
    float pd = q0.x * k0.x + q0.y * k0.y + q0.z * k0.z + q0.w * k0.w +
               q1.x * k1.x + q1.y * k1.y + q1.z * k1.z + q1.w * k1.w;
    pd += __shfl_xor(pd, 1, 64);
    pd += __shfl_xor(pd, 2, 64);  // full 32-dot in all 4 dim-qtr lanes
    float p = act ? __expf(pd * SCALE) : 0.f;
    s += p;
    const float4* vp = (const float4*)(V + (size_t)ei * DIM + h * DH + g * 8);
    float4 v0 = vp[0], v1 = vp[1];
    a0.x = fmaf(p, v0.x, a0.x); a0.y = fmaf(p, v0.y, a0.y);
    a0.z = fmaf(p, v0.z, a0.z); a0.w = fmaf(p, v0.w, a0.w);
    a1.x = fmaf(p, v1.x, a1.x); a1.y = fmaf(p, v1.y, a1.y);
    a1.z = fmaf(p, v1.z, a1.z); a1.w = fmaf(p, v1.w, a1.w);
  }
#pragma unroll
  for (int o = 4; o <= 8; o <<= 1) {
    s += __shfl_xor(s, o, 64);
    a0.x += __shfl_xor(a0.x, o, 64); a0.y += __shfl_xor(a0.y, o, 64);
    a0.z += __shfl_xor(a0.z, o, 64); a0.w += __shfl_xor(a0.w, o, 64);
    a1.x += __shfl_xor(a1.x, o, 64); a1.y += __shfl_xor(a1.y, o, 64);
    a1.z += __shfl_xor(a1.z, o, 64); a1.w += __shfl_xor(a1.w, o, 64);
  }
  if (j4 == 0) {
    float inv = 1.0f / s;
    float4* op = (float4*)(O + (size_t)qi * DIM + h * DH + g * 8);
    float4 r0 = {a0.x * inv, a0.y * inv, a0.z * inv, a0.w * inv};
    float4 r1 = {a1.x * inv, a1.y * inv, a1.z * inv, a1.w * inv};
    op[0] = r0;
    op[1] = r1;
  }
}

// ---------------- Final classifier GEMM: [4096,256]@[256,16]+b --------------
__global__ __launch_bounds__(256) void gemm_out_kernel(
    const float* __restrict__ Hm, const float* __restrict__ B,
    const float* __restrict__ bias, float* __restrict__ C) {
  __shared__ float Bs[256 * 16];
  int tid = threadIdx.x;
#pragma unroll
  for (int i = 0; i < 16; i++) Bs[i * 256 + tid] = B[i * 256 + tid];
  __syncthreads();
  int row = blockIdx.x * 16 + (tid >> 4);
  int col = tid & 15;
  const float* hp = Hm + (size_t)row * 256;
  float sacc = bias[col];
#pragma unroll 8
  for (int k = 0; k < 256; k++) sacc = fmaf(hp[k], Bs[k * 16 + col], sacc);
  C[(size_t)row * NCLS + col] = sacc;
}

extern "C" void kernel_launch(void* const* d_in, const int* in_sizes, int n_in,
                              void* d_out, int out_size, void* d_ws,
                              size_t ws_size, hipStream_t stream) {
  const float* nf = (const float*)d_in[0];
  const float* ef = (const float*)d_in[1];
  const int* ei = (const int*)d_in[2];
  const float* w_rn = (const float*)d_in[3];
  const float* b_rn = (const float*)d_in[4];
  const float* w_re = (const float*)d_in[5];
  const float* b_re = (const float*)d_in[6];
  const float* wq_n = (const float*)d_in[7];
  const float* bq_n = (const float*)d_in[8];
  const float* wk_n = (const float*)d_in[9];
  const float* bk_n = (const float*)d_in[10];
  const float* wv_n = (const float*)d_in[11];
  const float* bv_n = (const float*)d_in[12];
  const float* wo_n = (const float*)d_in[13];
  const float* bo_n = (const float*)d_in[14];
  const float* wq_e = (const float*)d_in[15];
  const float* bq_e = (const float*)d_in[16];
  const float* wk_e = (const float*)d_in[17];
  const float* bk_e = (const float*)d_in[18];
  const float* wv_e = (const float*)d_in[19];
  const float* bv_e = (const float*)d_in[20];
  const float* wo_e = (const float*)d_in[21];
  const float* bo_e = (const float*)d_in[22];
  const float* w_ne = (const float*)d_in[23];
  const float* b_ne = (const float*)d_in[24];
  const float* w_c1 = (const float*)d_in[25];
  const float* b_c1 = (const float*)d_in[26];
  const float* w_c2 = (const float*)d_in[27];
  const float* b_c2 = (const float*)d_in[28];

  const int* src = ei;
  const int* dst = ei + N_EDGES;

  float* ws = (float*)d_ws;
  size_t o = 0;
  float* ns = ws + o;   o += 2048;
  float* es = ws + o;   o += 4096;
  int* kidx = (int*)(ws + o); o += 2048;
  int* nkept = (int*)(ws + o); o += 64;
  int* nbr = (int*)(ws + o); o += (size_t)N_EDGES * NBR_CAP;
  int* degp = (int*)(ws + o); o += N_EDGES;
  float* qn = ws + o;   o += (size_t)N_NODES * DIM;
  float* kn = ws + o;   o += (size_t)N_NODES * DIM;
  float* vn = ws + o;   o += (size_t)N_NODES * DIM;
  float* qe = ws + o;   o += (size_t)N_EDGES * DIM;
  float* ke = ws + o;   o += (size_t)N_EDGES * DIM;
  float* ve = ws + o;   o += (size_t)N_EDGES * DIM;
  float* aon = ws + o;  o += (size_t)N_NODES * DIM;
  float* aoe = ws + o;  o += (size_t)N_EDGES * DIM;
  float* pn = ws + o;   o += (size_t)N_NODES * DIM;
  float* pe = ws + o;   o += (size_t)N_EDGES * DIM;
  float* ue = ws + o;   o += (size_t)N_EDGES * DIM;
  float* hb = ws + o;   o += (size_t)N_EDGES * 2 * DIM;
  float* ps = ws + o;   o += (size_t)N_NODES * HEADS * NSPLIT;
  float* pacc = hb;  // alias: pacc lifetime (steps 5-6) ends before hb (10-11)

  // 1. router scores
  score_kernel<<<dim3((N_NODES + N_EDGES) / 4), 256, 0, stream>>>(
      nf, ef, w_rn, b_rn, w_re, b_re, ns, es);
  // 2. top-k threshold + compacted kept-key list
  topk_kernel<<<1, 256, 0, stream>>>(ns, kidx, nkept);
  // 3. line-graph neighbor lists
  build_nbr_kernel<<<dim3(N_EDGES / 16), 1024, 0, stream>>>(src, dst, nbr,
                                                            degp);
  // 4. all six QKV projections (router gating fused into A-stage)
  gemm_qkv_kernel<<<dim3(96, 6), 256, 0, stream>>>(
      nf, ef, ns, es, wq_n, wk_n, wv_n, wq_e, wk_e, wv_e,
      bq_n, bk_n, bv_n, bq_e, bk_e, bv_e, qn, kn, vn, qe, ke, ve);
  // 5-6. node attention (key-split x4) + reduce
  attn_node_kernel<<<dim3(N_NODES / 16, HEADS, NSPLIT), 256, 0, stream>>>(
      qn, kn, vn, kidx, nkept, pacc, ps);
  attn_node_reduce_kernel<<<dim3(N_NODES * HEADS * DH / 256), 256, 0,
                            stream>>>(pacc, ps, aon);
  // 7. edge attention
  attn_edge_kernel<<<dim3(N_EDGES / 4), 256, 0, stream>>>(
      qe, ke, ve, nbr, degp, aoe);
  // 8. both output projections, one launch
  gemm_oproj_kernel<<<dim3(96, 2), 256, 0, stream>>>(
      aon, aoe, wo_n, wo_e, bo_n, bo_e, pn, pe);
  // 9. updated_edges = pe + (pn[src]+pn[dst]) @ w_ne + b_ne
  gemm_msg_kernel<<<dim3(64, 2), 256, 0, stream>>>(pn, src, dst, w_ne, b_ne,
                                                   pe, ue);
  // 10. h = gelu(ue @ w_c1 + b_c1)
  gemm_gelu_kernel<<<dim3(64, 4), 256, 0, stream>>>(ue, w_c1, b_c1, hb);
  // 11. out = h @ w_c2 + b_c2
  gemm_out_kernel<<<dim3(N_EDGES / 16), 256, 0, stream>>>(hb, w_c2, b_c2,
                                                          (float*)d_out);
}

// Round 5
// 139.835 us; speedup vs baseline: 5.1988x; 1.0054x over previous
//
#include <hip/hip_runtime.h>
#include <math.h>

#define N_NODES 2048
#define N_EDGES 4096
#define DIM 128
#define HEADS 4
#define DH 32
#define NCLS 16
#define TOPK 1024
#define NBR_CAP 64
#define NSPLIT 4
#define SCALE 0.17677669529663687f  // 1/sqrt(32)

__device__ __forceinline__ float wave_reduce_sum(float v) {
#pragma unroll
  for (int o = 32; o > 0; o >>= 1) v += __shfl_xor(v, o, 64);
  return v;
}

// ---------------- Scores only (gating folded into QKV GEMM) -----------------
__global__ __launch_bounds__(256) void score_kernel(
    const float* __restrict__ nf, const float* __restrict__ ef,
    const float* __restrict__ w_rn, const float* __restrict__ b_rn,
    const float* __restrict__ w_re, const float* __restrict__ b_re,
    float* __restrict__ ns, float* __restrict__ es) {
  int wid = threadIdx.x >> 6, lane = threadIdx.x & 63;
  int row = blockIdx.x * 4 + wid;
  const float* feat;
  const float* w;
  float b;
  float* scp;
  if (row < N_NODES) {
    feat = nf + (size_t)row * DIM;
    w = w_rn; b = b_rn[0];
    scp = ns + row;
  } else {
    int r = row - N_NODES;
    feat = ef + (size_t)r * DIM;
    w = w_re; b = b_re[0];
    scp = es + r;
  }
  float d = feat[lane] * w[lane] + feat[lane + 64] * w[lane + 64];
  d = wave_reduce_sum(d);
  if (lane == 0) *scp = 1.0f / (1.0f + __expf(-(d + b)));
}

// ---------------- Top-k: single-wave binary search + block compact ----------
// kth largest = max{v : count(s >= v) >= k}. Wave 0 holds all 2048 score bit
// patterns in registers (32/lane); the ~30 dependent search rounds use only
// wave shuffles (no block syncs). Sigmoid scores in (0,1) -> positive floats
// -> bit order == value order. 64-bit midpoint (u32 overflow hung round 1).
__global__ __launch_bounds__(256) void topk_kernel(
    const float* __restrict__ ns, int* __restrict__ kidx,
    int* __restrict__ nkept) {
  __shared__ unsigned sh_lo;
  __shared__ int wcnt;
  int tid = threadIdx.x;
  if (tid == 0) wcnt = 0;
  if (tid < 64) {
    unsigned bv[32];
#pragma unroll
    for (int i = 0; i < 32; i++)
      bv[i] = __float_as_uint(ns[tid * 32 + i]);
    unsigned lo = 0u, hi = 0x3F800000u;  // scores < 1.0f
    while (lo < hi) {
      unsigned mid = (unsigned)(((unsigned long long)lo + hi + 1ull) >> 1);
      int c = 0;
#pragma unroll
      for (int i = 0; i < 32; i++) c += (bv[i] >= mid);
#pragma unroll
      for (int o = 1; o < 64; o <<= 1) c += __shfl_xor(c, o, 64);
      if (c >= TOPK) lo = mid; else hi = mid - 1;
    }
    if (tid == 0) sh_lo = lo;
  }
  __syncthreads();
  unsigned lo = sh_lo;
#pragma unroll
  for (int i = 0; i < 8; i++) {
    int idx = tid * 8 + i;
    if (__float_as_uint(ns[idx]) >= lo) kidx[atomicAdd(&wcnt, 1)] = idx;
  }
  __syncthreads();
  if (tid == 0) nkept[0] = wcnt;
}

// ---------------- Line-graph adjacency -> fixed-cap neighbor lists ----------
// 16 queries/block; src/dst staged once in LDS (32 KB) so the 16 waves scan
// LDS instead of 16x-redundant L2 reads. deg ~ 9; P(deg > 64) ~ 1e-30.
__global__ __launch_bounds__(1024) void build_nbr_kernel(
    const int* __restrict__ src, const int* __restrict__ dst,
    int* __restrict__ nbr, int* __restrict__ deg) {
  __shared__ int sL[N_EDGES];
  __shared__ int dL[N_EDGES];
  __shared__ int cnt[16];
  int tid = threadIdx.x;
  int w = tid >> 6, lane = tid & 63;
#pragma unroll
  for (int i = 0; i < 4; i++) {
    int j = i * 1024 + tid;
    sL[j] = src[j];
    dL[j] = dst[j];
  }
  if (lane == 0) cnt[w] = 0;
  __syncthreads();
  int qi = blockIdx.x * 16 + w;
  int sq = sL[qi], dq = dL[qi];
  for (int j = lane; j < N_EDGES; j += 64) {
    int sj = sL[j], dj = dL[j];
    if (sj == sq || sj == dq || dj == sq || dj == dq) {
      int pos = atomicAdd(&cnt[w], 1);
      if (pos < NBR_CAP) nbr[(size_t)qi * NBR_CAP + pos] = j;
    }
  }
  __syncthreads();
  if (lane == 0) deg[qi] = min(cnt[w], NBR_CAP);
}

// ---------------- Fused QKV projections with router gating -----------------
// A-row gated by score on LDS-stage: As = A[row] * score[row]. grid (96, 6).
__global__ __launch_bounds__(256) void gemm_qkv_kernel(
    const float* __restrict__ nf, const float* __restrict__ ef,
    const float* __restrict__ ns, const float* __restrict__ es,
    const float* __restrict__ wq_n, const float* __restrict__ wk_n,
    const float* __restrict__ wv_n, const float* __restrict__ wq_e,
    const float* __restrict__ wk_e, const float* __restrict__ wv_e,
    const float* __restrict__ bq_n, const float* __restrict__ bk_n,
    const float* __restrict__ bv_n, const float* __restrict__ bq_e,
    const float* __restrict__ bk_e, const float* __restrict__ bv_e,
    float* __restrict__ qn, float* __restrict__ kn, float* __restrict__ vn,
    float* __restrict__ qe, float* __restrict__ ke, float* __restrict__ ve) {
  __shared__ float As[16][68];
  __shared__ float Bs[16][68];
  __shared__ float ss[64];
  int bx = blockIdx.x;
  int mat = blockIdx.y >> 1;
  int bn = (blockIdx.y & 1) * 64;
  bool edge = bx >= 32;
  int bm = edge ? (bx - 32) * 64 : bx * 64;
  const float* A = edge ? ef : nf;
  const float* sc = edge ? es : ns;
  const float* W;
  const float* bias;
  float* C;
  if (!edge) {
    if (mat == 0) { W = wq_n; bias = bq_n; C = qn; }
    else if (mat == 1) { W = wk_n; bias = bk_n; C = kn; }
    else { W = wv_n; bias = bv_n; C = vn; }
  } else {
    if (mat == 0) { W = wq_e; bias = bq_e; C = qe; }
    else if (mat == 1) { W = wk_e; bias = bk_e; C = ke; }
    else { W = wv_e; bias = bv_e; C = ve; }
  }
  int tid = threadIdx.x;
  if (tid < 64) ss[tid] = sc[bm + tid];
  __syncthreads();
  int tm = (tid >> 4) * 4, tn = (tid & 15) * 4;
  float4 acc[4] = {{0,0,0,0},{0,0,0,0},{0,0,0,0},{0,0,0,0}};
  for (int k0 = 0; k0 < DIM; k0 += 16) {
#pragma unroll
    for (int i = 0; i < 4; i++) {
      int e = i * 256 + tid;
      int r = e >> 4, kk = e & 15;
      As[kk][r] = A[(size_t)(bm + r) * DIM + k0 + kk] * ss[r];
      int kb = e >> 6, c = e & 63;
      Bs[kb][c] = W[(size_t)(k0 + kb) * DIM + bn + c];
    }
    __syncthreads();
#pragma unroll
    for (int kk = 0; kk < 16; kk++) {
      float4 a = *(const float4*)&As[kk][tm];
      float4 b = *(const float4*)&Bs[kk][tn];
      acc[0].x = fmaf(a.x, b.x, acc[0].x); acc[0].y = fmaf(a.x, b.y, acc[0].y);
      acc[0].z = fmaf(a.x, b.z, acc[0].z); acc[0].w = fmaf(a.x, b.w, acc[0].w);
      acc[1].x = fmaf(a.y, b.x, acc[1].x); acc[1].y = fmaf(a.y, b.y, acc[1].y);
      acc[1].z = fmaf(a.y, b.z, acc[1].z); acc[1].w = fmaf(a.y, b.w, acc[1].w);
      acc[2].x = fmaf(a.z, b.x, acc[2].x); acc[2].y = fmaf(a.z, b.y, acc[2].y);
      acc[2].z = fmaf(a.z, b.z, acc[2].z); acc[2].w = fmaf(a.z, b.w, acc[2].w);
      acc[3].x = fmaf(a.w, b.x, acc[3].x); acc[3].y = fmaf(a.w, b.y, acc[3].y);
      acc[3].z = fmaf(a.w, b.z, acc[3].z); acc[3].w = fmaf(a.w, b.w, acc[3].w);
    }
    __syncthreads();
  }
  float4 b4 = *(const float4*)&bias[bn + tn];
#pragma unroll
  for (int i = 0; i < 4; i++) {
    float4 r;
    r.x = acc[i].x + b4.x; r.y = acc[i].y + b4.y;
    r.z = acc[i].z + b4.z; r.w = acc[i].w + b4.w;
    *(float4*)&C[(size_t)(bm + tm + i) * DIM + bn + tn] = r;
  }
}

// ---------------- Shared 64x64 f32 GEMM tile body (K=128, float4 LDS) -------
__device__ __forceinline__ void gemm_body(
    float (&As)[16][68], float (&Bs)[16][68],
    const float* __restrict__ A, const float* __restrict__ B,
    int bm, int bn, int N, float4 (&acc)[4], int tid) {
  int tm = (tid >> 4) * 4, tn = (tid & 15) * 4;
  for (int k0 = 0; k0 < DIM; k0 += 16) {
#pragma unroll
    for (int i = 0; i < 4; i++) {
      int e = i * 256 + tid;
      int r = e >> 4, kk = e & 15;
      As[kk][r] = A[(size_t)(bm + r) * DIM + k0 + kk];
      int kb = e >> 6, c = e & 63;
      Bs[kb][c] = B[(size_t)(k0 + kb) * N + bn + c];
    }
    __syncthreads();
#pragma unroll
    for (int kk = 0; kk < 16; kk++) {
      float4 a = *(const float4*)&As[kk][tm];
      float4 b = *(const float4*)&Bs[kk][tn];
      acc[0].x = fmaf(a.x, b.x, acc[0].x); acc[0].y = fmaf(a.x, b.y, acc[0].y);
      acc[0].z = fmaf(a.x, b.z, acc[0].z); acc[0].w = fmaf(a.x, b.w, acc[0].w);
      acc[1].x = fmaf(a.y, b.x, acc[1].x); acc[1].y = fmaf(a.y, b.y, acc[1].y);
      acc[1].z = fmaf(a.y, b.z, acc[1].z); acc[1].w = fmaf(a.y, b.w, acc[1].w);
      acc[2].x = fmaf(a.z, b.x, acc[2].x); acc[2].y = fmaf(a.z, b.y, acc[2].y);
      acc[2].z = fmaf(a.z, b.z, acc[2].z); acc[2].w = fmaf(a.z, b.w, acc[2].w);
      acc[3].x = fmaf(a.w, b.x, acc[3].x); acc[3].y = fmaf(a.w, b.y, acc[3].y);
      acc[3].z = fmaf(a.w, b.z, acc[3].z); acc[3].w = fmaf(a.w, b.w, acc[3].w);
    }
    __syncthreads();
  }
}

// ---------------- Fused output projections (node + edge) --------------------
__global__ __launch_bounds__(256) void gemm_oproj_kernel(
    const float* __restrict__ aon, const float* __restrict__ aoe,
    const float* __restrict__ wo_n, const float* __restrict__ wo_e,
    const float* __restrict__ bo_n, const float* __restrict__ bo_e,
    float* __restrict__ pn, float* __restrict__ pe) {
  __shared__ float As[16][68];
  __shared__ float Bs[16][68];
  int bx = blockIdx.x;
  int bn = blockIdx.y * 64;
  bool edge = bx >= 32;
  int bm = edge ? (bx - 32) * 64 : bx * 64;
  const float* A = edge ? aoe : aon;
  const float* W = edge ? wo_e : wo_n;
  const float* bias = edge ? bo_e : bo_n;
  float* C = edge ? pe : pn;
  float4 acc[4] = {{0,0,0,0},{0,0,0,0},{0,0,0,0},{0,0,0,0}};
  int tid = threadIdx.x;
  gemm_body(As, Bs, A, W, bm, bn, DIM, acc, tid);
  int tm = (tid >> 4) * 4, tn = (tid & 15) * 4;
  float4 b4 = *(const float4*)&bias[bn + tn];
#pragma unroll
  for (int i = 0; i < 4; i++) {
    float4 r;
    r.x = acc[i].x + b4.x; r.y = acc[i].y + b4.y;
    r.z = acc[i].z + b4.z; r.w = acc[i].w + b4.w;
    *(float4*)&C[(size_t)(bm + tm + i) * DIM + bn + tn] = r;
  }
}

// ---------------- Gather GEMM: C = (NO[src]+NO[dst])@B + bias + EO ----------
__global__ __launch_bounds__(256) void gemm_msg_kernel(
    const float* __restrict__ NO, const int* __restrict__ src,
    const int* __restrict__ dst, const float* __restrict__ B,
    const float* __restrict__ bias, const float* __restrict__ EO,
    float* __restrict__ C) {
  __shared__ float As[16][68];
  __shared__ float Bs[16][68];
  int bm = blockIdx.x * 64, bn = blockIdx.y * 64;
  int tid = threadIdx.x;
  int tm = (tid >> 4) * 4, tn = (tid & 15) * 4;
  float4 acc[4] = {{0,0,0,0},{0,0,0,0},{0,0,0,0},{0,0,0,0}};
  for (int k0 = 0; k0 < DIM; k0 += 16) {
#pragma unroll
    for (int i = 0; i < 4; i++) {
      int e = i * 256 + tid;
      int r = e >> 4, kk = e & 15;
      int row = bm + r;
      int s0 = src[row], d0 = dst[row];
      As[kk][r] = NO[(size_t)s0 * DIM + k0 + kk] + NO[(size_t)d0 * DIM + k0 + kk];
      int kb = e >> 6, c = e & 63;
      Bs[kb][c] = B[(size_t)(k0 + kb) * DIM + bn + c];
    }
    __syncthreads();
#pragma unroll
    for (int kk = 0; kk < 16; kk++) {
      float4 a = *(const float4*)&As[kk][tm];
      float4 b = *(const float4*)&Bs[kk][tn];
      acc[0].x = fmaf(a.x, b.x, acc[0].x); acc[0].y = fmaf(a.x, b.y, acc[0].y);
      acc[0].z = fmaf(a.x, b.z, acc[0].z); acc[0].w = fmaf(a.x, b.w, acc[0].w);
      acc[1].x = fmaf(a.y, b.x, acc[1].x); acc[1].y = fmaf(a.y, b.y, acc[1].y);
      acc[1].z = fmaf(a.y, b.z, acc[1].z); acc[1].w = fmaf(a.y, b.w, acc[1].w);
      acc[2].x = fmaf(a.z, b.x, acc[2].x); acc[2].y = fmaf(a.z, b.y, acc[2].y);
      acc[2].z = fmaf(a.z, b.z, acc[2].z); acc[2].w = fmaf(a.z, b.w, acc[2].w);
      acc[3].x = fmaf(a.w, b.x, acc[3].x); acc[3].y = fmaf(a.w, b.y, acc[3].y);
      acc[3].z = fmaf(a.w, b.z, acc[3].z); acc[3].w = fmaf(a.w, b.w, acc[3].w);
    }
    __syncthreads();
  }
  float4 b4 = *(const float4*)&bias[bn + tn];
#pragma unroll
  for (int i = 0; i < 4; i++) {
    size_t idx = (size_t)(bm + tm + i) * DIM + bn + tn;
    float4 e4 = *(const float4*)&EO[idx];
    float4 r;
    r.x = acc[i].x + b4.x + e4.x; r.y = acc[i].y + b4.y + e4.y;
    r.z = acc[i].z + b4.z + e4.z; r.w = acc[i].w + b4.w + e4.w;
    *(float4*)&C[idx] = r;
  }
}

// ---------------- GELU GEMM: h = gelu(ue @ w_c1 + b), N=256 -----------------
__global__ __launch_bounds__(256) void gemm_gelu_kernel(
    const float* __restrict__ A, const float* __restrict__ B,
    const float* __restrict__ bias, float* __restrict__ C) {
  __shared__ float As[16][68];
  __shared__ float Bs[16][68];
  int bm = blockIdx.x * 64, bn = blockIdx.y * 64;
  int tid = threadIdx.x;
  float4 acc[4] = {{0,0,0,0},{0,0,0,0},{0,0,0,0},{0,0,0,0}};
  gemm_body(As, Bs, A, B, bm, bn, 256, acc, tid);
  int tm = (tid >> 4) * 4, tn = (tid & 15) * 4;
  float4 b4 = *(const float4*)&bias[bn + tn];
#pragma unroll
  for (int i = 0; i < 4; i++) {
    float vv[4] = {acc[i].x + b4.x, acc[i].y + b4.y, acc[i].z + b4.z,
                   acc[i].w + b4.w};
#pragma unroll
    for (int j = 0; j < 4; j++) {
      float v = vv[j];
      float u = 0.7978845608028654f * (v + 0.044715f * v * v * v);
      vv[j] = 0.5f * v * (1.0f + tanhf(u));
    }
    float4 r = {vv[0], vv[1], vv[2], vv[3]};
    *(float4*)&C[(size_t)(bm + tm + i) * 256 + bn + tn] = r;
  }
}

// ---------------- Node attention, key-split x4 ------------------------------
// grid (128, H, NSPLIT). Block: 16 queries x 16 key-slices over its quarter
// of the kept keys; emits partial (acc[32], sum) per (q, h, split). Scores
// tiny (|s|<~0.1) -> exp cannot overflow -> no running max needed.
__global__ __launch_bounds__(256) void attn_node_kernel(
    const float* __restrict__ Q, const float* __restrict__ K,
    const float* __restrict__ V, const int* __restrict__ kidx,
    const int* __restrict__ nkeptp, float* __restrict__ pacc,
    float* __restrict__ ps) {
  __shared__ float Ks[64][36];
  __shared__ float Vs[64][36];
  int h = blockIdx.y;
  int sp = blockIdx.z;
  int tid = threadIdx.x;
  int q = tid >> 4, e = tid & 15;
  int qi = blockIdx.x * 16 + q;
  int nkept = nkeptp[0];
  int spl = (nkept + NSPLIT - 1) / NSPLIT;
  int start = sp * spl;
  int end = min(start + spl, nkept);
  float4 qv[8];
  const float4* qp = (const float4*)(Q + (size_t)qi * DIM + h * DH);
#pragma unroll
  for (int i = 0; i < 8; i++) qv[i] = qp[i];
  float s = 0.f;
  float4 acc[8];
#pragma unroll
  for (int i = 0; i < 8; i++) acc[i] = make_float4(0.f, 0.f, 0.f, 0.f);

  for (int t0 = start; t0 < end; t0 += 64) {
#pragma unroll
    for (int i = 0; i < 8; i++) {
      int e2 = i * 256 + tid;
      int r = e2 >> 5, d = e2 & 31;
      int row = t0 + r;
      int ki = (row < end) ? kidx[row] : kidx[0];
      Ks[r][d] = K[(size_t)ki * DIM + h * DH + d];
      Vs[r][d] = V[(size_t)ki * DIM + h * DH + d];
    }
    __syncthreads();
    int nk = end - t0;
    if (nk > 64) nk = 64;
#pragma unroll
    for (int j8 = 0; j8 < 4; j8++) {
      int j = j8 * 16 + e;
      if (j < nk) {
        const float4* kr = (const float4*)&Ks[j][0];
        const float4* vr = (const float4*)&Vs[j][0];
        float4 psum = make_float4(0.f, 0.f, 0.f, 0.f);
#pragma unroll
        for (int i = 0; i < 8; i++) {
          float4 kv = kr[i];
          psum.x = fmaf(qv[i].x, kv.x, psum.x);
          psum.y = fmaf(qv[i].y, kv.y, psum.y);
          psum.z = fmaf(qv[i].z, kv.z, psum.z);
          psum.w = fmaf(qv[i].w, kv.w, psum.w);
        }
        float p = __expf(((psum.x + psum.y) + (psum.z + psum.w)) * SCALE);
        s += p;
#pragma unroll
        for (int i = 0; i < 8; i++) {
          float4 vv = vr[i];
          acc[i].x = fmaf(p, vv.x, acc[i].x);
          acc[i].y = fmaf(p, vv.y, acc[i].y);
          acc[i].z = fmaf(p, vv.z, acc[i].z);
          acc[i].w = fmaf(p, vv.w, acc[i].w);
        }
      }
    }
    __syncthreads();
  }
  // reduce over the 16 key-slices (bits 0..3 of the lane id)
#pragma unroll
  for (int o = 1; o <= 8; o <<= 1) {
    s += __shfl_xor(s, o, 64);
#pragma unroll
    for (int i = 0; i < 8; i++) {
      acc[i].x += __shfl_xor(acc[i].x, o, 64);
      acc[i].y += __shfl_xor(acc[i].y, o, 64);
      acc[i].z += __shfl_xor(acc[i].z, o, 64);
      acc[i].w += __shfl_xor(acc[i].w, o, 64);
    }
  }
  if (e == 0) {
    size_t idx = ((size_t)qi * HEADS + h) * NSPLIT + sp;
    float4* pp = (float4*)(pacc + idx * 32);
#pragma unroll
    for (int i = 0; i < 8; i++) pp[i] = acc[i];
    ps[idx] = s;
  }
}

// ---------------- Node attention reduce: combine splits, normalize ----------
__global__ __launch_bounds__(256) void attn_node_reduce_kernel(
    const float* __restrict__ pacc, const float* __restrict__ ps,
    float* __restrict__ O) {
  int gid = blockIdx.x * 256 + threadIdx.x;
  int qh = gid >> 5, d = gid & 31;
  int q = qh >> 2, h = qh & 3;
  float ssum = 0.f, v = 0.f;
#pragma unroll
  for (int sp = 0; sp < NSPLIT; sp++) {
    size_t idx = (size_t)qh * NSPLIT + sp;
    ssum += ps[idx];
    v += pacc[idx * 32 + d];
  }
  O[(size_t)q * DIM + h * DH + d] = v / ssum;
}

// ---------------- Edge attention over neighbor lists ------------------------
// Block = 4 query edges; wave = head; lane = (q 2b | nbr-slot 2b | dim-qtr 2b).
__global__ __launch_bounds__(256) void attn_edge_kernel(
    const float* __restrict__ Q, const float* __restrict__ Km,
    const float* __restrict__ V, const int* __restrict__ nbr,
    const int* __restrict__ deg, float* __restrict__ O) {
  int h = threadIdx.x >> 6;
  int lane = threadIdx.x & 63;
  int ql = lane >> 4, j4 = (lane >> 2) & 3, g = lane & 3;
  int qi = blockIdx.x * 4 + ql;
  int dg = deg[qi];
  const float4* qp = (const float4*)(Q + (size_t)qi * DIM + h * DH + g * 8);
  float4 q0 = qp[0], q1 = qp[1];
  float s = 0.f;
  float4 a0 = make_float4(0.f, 0.f, 0.f, 0.f);
  float4 a1 = make_float4(0.f, 0.f, 0.f, 0.f);
  for (int c0 = 0; c0 < dg; c0 += 4) {
    int j = c0 + j4;
    bool act = j < dg;
    int ei = act ? nbr[(size_t)qi * NBR_CAP + j] : 0;
    const float4* kp = (const float4*)(Km + (size_t)ei * DIM + h * DH + g * 8);
    float4 k0 = kp[0], k1 = kp[1];
    float pd = q0.x * k0.x + q0.y * k0.y + q0.z * k0.z + q0.w * k0.w +
               q1.x * k1.x + q1.y * k1.y + q1.z * k1.z + q1.w * k1.w;
    pd += __shfl_xor(pd, 1, 64);
    pd += __shfl_xor(pd, 2, 64);  // full 32-dot in all 4 dim-qtr lanes
    float p = act ? __expf(pd * SCALE) : 0.f;
    s += p;
    const float4* vp = (const float4*)(V + (size_t)ei * DIM + h * DH + g * 8);
    float4 v0 = vp[0], v1 = vp[1];
    a0.x = fmaf(p, v0.x, a0.x); a0.y = fmaf(p, v0.y, a0.y);
    a0.z = fmaf(p, v0.z, a0.z); a0.w = fmaf(p, v0.w, a0.w);
    a1.x = fmaf(p, v1.x, a1.x); a1.y = fmaf(p, v1.y, a1.y);
    a1.z = fmaf(p, v1.z, a1.z); a1.w = fmaf(p, v1.w, a1.w);
  }
#pragma unroll
  for (int o = 4; o <= 8; o <<= 1) {
    s += __shfl_xor(s, o, 64);
    a0.x += __shfl_xor(a0.x, o, 64); a0.y += __shfl_xor(a0.y, o, 64);
    a0.z += __shfl_xor(a0.z, o, 64); a0.w += __shfl_xor(a0.w, o, 64);
    a1.x += __shfl_xor(a1.x, o, 64); a1.y += __shfl_xor(a1.y, o, 64);
    a1.z += __shfl_xor(a1.z, o, 64); a1.w += __shfl_xor(a1.w, o, 64);
  }
  if (j4 == 0) {
    float inv = 1.0f / s;
    float4* op = (float4*)(O + (size_t)qi * DIM + h * DH + g * 8);
    float4 r0 = {a0.x * inv, a0.y * inv, a0.z * inv, a0.w * inv};
    float4 r1 = {a1.x * inv, a1.y * inv, a1.z * inv, a1.w * inv};
    op[0] = r0;
    op[1] = r1;
  }
}

// ---------------- Final classifier GEMM: [4096,256]@[256,16]+b --------------
__global__ __launch_bounds__(256) void gemm_out_kernel(
    const float* __restrict__ Hm, const float* __restrict__ B,
    const float* __restrict__ bias, float* __restrict__ C) {
  __shared__ float Bs[256 * 16];
  int tid = threadIdx.x;
#pragma unroll
  for (int i = 0; i < 16; i++) Bs[i * 256 + tid] = B[i * 256 + tid];
  __syncthreads();
  int row = blockIdx.x * 16 + (tid >> 4);
  int col = tid & 15;
  const float* hp = Hm + (size_t)row * 256;
  float sacc = bias[col];
#pragma unroll 8
  for (int k = 0; k < 256; k++) sacc = fmaf(hp[k], Bs[k * 16 + col], sacc);
  C[(size_t)row * NCLS + col] = sacc;
}

extern "C" void kernel_launch(void* const* d_in, const int* in_sizes, int n_in,
                              void* d_out, int out_size, void* d_ws,
                              size_t ws_size, hipStream_t stream) {
  const float* nf = (const float*)d_in[0];
  const float* ef = (const float*)d_in[1];
  const int* ei = (const int*)d_in[2];
  const float* w_rn = (const float*)d_in[3];
  const float* b_rn = (const float*)d_in[4];
  const float* w_re = (const float*)d_in[5];
  const float* b_re = (const float*)d_in[6];
  const float* wq_n = (const float*)d_in[7];
  const float* bq_n = (const float*)d_in[8];
  const float* wk_n = (const float*)d_in[9];
  const float* bk_n = (const float*)d_in[10];
  const float* wv_n = (const float*)d_in[11];
  const float* bv_n = (const float*)d_in[12];
  const float* wo_n = (const float*)d_in[13];
  const float* bo_n = (const float*)d_in[14];
  const float* wq_e = (const float*)d_in[15];
  const float* bq_e = (const float*)d_in[16];
  const float* wk_e = (const float*)d_in[17];
  const float* bk_e = (const float*)d_in[18];
  const float* wv_e = (const float*)d_in[19];
  const float* bv_e = (const float*)d_in[20];
  const float* wo_e = (const float*)d_in[21];
  const float* bo_e = (const float*)d_in[22];
  const float* w_ne = (const float*)d_in[23];
  const float* b_ne = (const float*)d_in[24];
  const float* w_c1 = (const float*)d_in[25];
  const float* b_c1 = (const float*)d_in[26];
  const float* w_c2 = (const float*)d_in[27];
  const float* b_c2 = (const float*)d_in[28];

  const int* src = ei;
  const int* dst = ei + N_EDGES;

  float* ws = (float*)d_ws;
  size_t o = 0;
  float* ns = ws + o;   o += 2048;
  float* es = ws + o;   o += 4096;
  int* kidx = (int*)(ws + o); o += 2048;
  int* nkept = (int*)(ws + o); o += 64;
  int* nbr = (int*)(ws + o); o += (size_t)N_EDGES * NBR_CAP;
  int* degp = (int*)(ws + o); o += N_EDGES;
  float* qn = ws + o;   o += (size_t)N_NODES * DIM;
  float* kn = ws + o;   o += (size_t)N_NODES * DIM;
  float* vn = ws + o;   o += (size_t)N_NODES * DIM;
  float* qe = ws + o;   o += (size_t)N_EDGES * DIM;
  float* ke = ws + o;   o += (size_t)N_EDGES * DIM;
  float* ve = ws + o;   o += (size_t)N_EDGES * DIM;
  float* aon = ws + o;  o += (size_t)N_NODES * DIM;
  float* aoe = ws + o;  o += (size_t)N_EDGES * DIM;
  float* pn = ws + o;   o += (size_t)N_NODES * DIM;
  float* pe = ws + o;   o += (size_t)N_EDGES * DIM;
  float* ue = ws + o;   o += (size_t)N_EDGES * DIM;
  float* hb = ws + o;   o += (size_t)N_EDGES * 2 * DIM;
  float* ps = ws + o;   o += (size_t)N_NODES * HEADS * NSPLIT;
  float* pacc = hb;  // alias: pacc lifetime (steps 5-6) ends before hb (10-11)

  // 1. router scores
  score_kernel<<<dim3((N_NODES + N_EDGES) / 4), 256, 0, stream>>>(
      nf, ef, w_rn, b_rn, w_re, b_re, ns, es);
  // 2. top-k threshold + compacted kept-key list
  topk_kernel<<<1, 256, 0, stream>>>(ns, kidx, nkept);
  // 3. line-graph neighbor lists
  build_nbr_kernel<<<dim3(N_EDGES / 16), 1024, 0, stream>>>(src, dst, nbr,
                                                            degp);
  // 4. all six QKV projections (router gating fused into A-stage)
  gemm_qkv_kernel<<<dim3(96, 6), 256, 0, stream>>>(
      nf, ef, ns, es, wq_n, wk_n, wv_n, wq_e, wk_e, wv_e,
      bq_n, bk_n, bv_n, bq_e, bk_e, bv_e, qn, kn, vn, qe, ke, ve);
  // 5-6. node attention (key-split x4) + reduce
  attn_node_kernel<<<dim3(N_NODES / 16, HEADS, NSPLIT), 256, 0, stream>>>(
      qn, kn, vn, kidx, nkept, pacc, ps);
  attn_node_reduce_kernel<<<dim3(N_NODES * HEADS * DH / 256), 256, 0,
                            stream>>>(pacc, ps, aon);
  // 7. edge attention
  attn_edge_kernel<<<dim3(N_EDGES / 4), 256, 0, stream>>>(
      qe, ke, ve, nbr, degp, aoe);
  // 8. both output projections, one launch
  gemm_oproj_kernel<<<dim3(96, 2), 256, 0, stream>>>(
      aon, aoe, wo_n, wo_e, bo_n, bo_e, pn, pe);
  // 9. updated_edges = pe + (pn[src]+pn[dst]) @ w_ne + b_ne
  gemm_msg_kernel<<<dim3(64, 2), 256, 0, stream>>>(pn, src, dst, w_ne, b_ne,
                                                   pe, ue);
  // 10. h = gelu(ue @ w_c1 + b_c1)
  gemm_gelu_kernel<<<dim3(64, 4), 256, 0, stream>>>(ue, w_c1, b_c1, hb);
  // 11. out = h @ w_c2 + b_c2
  gemm_out_kernel<<<dim3(N_EDGES / 16), 256, 0, stream>>>(hb, w_c2, b_c2,
                                                          (float*)d_out);
}

// Round 6
// 130.175 us; speedup vs baseline: 5.5846x; 1.0742x over previous
//
#include <hip/hip_runtime.h>
#include <math.h>

#define N_NODES 2048
#define N_EDGES 4096
#define DIM 128
#define HEADS 4
#define DH 32
#define NCLS 16
#define TOPK 1024
#define NBR_CAP 64
#define NSPLIT 2
#define QB 32  // queries per attn_node block
#define TQ 4   // queries per thread
#define SCALE 0.17677669529663687f  // 1/sqrt(32)

__device__ __forceinline__ float wave_reduce_sum(float v) {
#pragma unroll
  for (int o = 32; o > 0; o >>= 1) v += __shfl_xor(v, o, 64);
  return v;
}

// ---------------- Scores only (gating folded into QKV GEMM) -----------------
__global__ __launch_bounds__(256) void score_kernel(
    const float* __restrict__ nf, const float* __restrict__ ef,
    const float* __restrict__ w_rn, const float* __restrict__ b_rn,
    const float* __restrict__ w_re, const float* __restrict__ b_re,
    float* __restrict__ ns, float* __restrict__ es) {
  int wid = threadIdx.x >> 6, lane = threadIdx.x & 63;
  int row = blockIdx.x * 4 + wid;
  const float* feat;
  const float* w;
  float b;
  float* scp;
  if (row < N_NODES) {
    feat = nf + (size_t)row * DIM;
    w = w_rn; b = b_rn[0];
    scp = ns + row;
  } else {
    int r = row - N_NODES;
    feat = ef + (size_t)r * DIM;
    w = w_re; b = b_re[0];
    scp = es + r;
  }
  float d = feat[lane] * w[lane] + feat[lane + 64] * w[lane + 64];
  d = wave_reduce_sum(d);
  if (lane == 0) *scp = 1.0f / (1.0f + __expf(-(d + b)));
}

// ---------------- Top-k: single-wave binary search + block compact ----------
// kth largest = max{v : count(s >= v) >= k}. Wave 0 holds all 2048 score bit
// patterns in registers (32/lane); dependent search rounds use only wave
// shuffles. Sigmoid scores in (0,1) -> positive floats -> bit order == value
// order. 64-bit midpoint (u32 overflow hung round 1).
__global__ __launch_bounds__(256) void topk_kernel(
    const float* __restrict__ ns, int* __restrict__ kidx,
    int* __restrict__ nkept) {
  __shared__ unsigned sh_lo;
  __shared__ int wcnt;
  int tid = threadIdx.x;
  if (tid == 0) wcnt = 0;
  if (tid < 64) {
    unsigned bv[32];
#pragma unroll
    for (int i = 0; i < 32; i++)
      bv[i] = __float_as_uint(ns[tid * 32 + i]);
    unsigned lo = 0u, hi = 0x3F800000u;  // scores < 1.0f
    while (lo < hi) {
      unsigned mid = (unsigned)(((unsigned long long)lo + hi + 1ull) >> 1);
      int c = 0;
#pragma unroll
      for (int i = 0; i < 32; i++) c += (bv[i] >= mid);
#pragma unroll
      for (int o = 1; o < 64; o <<= 1) c += __shfl_xor(c, o, 64);
      if (c >= TOPK) lo = mid; else hi = mid - 1;
    }
    if (tid == 0) sh_lo = lo;
  }
  __syncthreads();
  unsigned lo = sh_lo;
#pragma unroll
  for (int i = 0; i < 8; i++) {
    int idx = tid * 8 + i;
    if (__float_as_uint(ns[idx]) >= lo) kidx[atomicAdd(&wcnt, 1)] = idx;
  }
  __syncthreads();
  if (tid == 0) nkept[0] = wcnt;
}

// ---------------- Line-graph adjacency -> fixed-cap neighbor lists ----------
// 16 queries/block; src/dst staged once in LDS (32 KB). deg ~ 9.
__global__ __launch_bounds__(1024) void build_nbr_kernel(
    const int* __restrict__ src, const int* __restrict__ dst,
    int* __restrict__ nbr, int* __restrict__ deg) {
  __shared__ int sL[N_EDGES];
  __shared__ int dL[N_EDGES];
  __shared__ int cnt[16];
  int tid = threadIdx.x;
  int w = tid >> 6, lane = tid & 63;
#pragma unroll
  for (int i = 0; i < 4; i++) {
    int j = i * 1024 + tid;
    sL[j] = src[j];
    dL[j] = dst[j];
  }
  if (lane == 0) cnt[w] = 0;
  __syncthreads();
  int qi = blockIdx.x * 16 + w;
  int sq = sL[qi], dq = dL[qi];
  for (int j = lane; j < N_EDGES; j += 64) {
    int sj = sL[j], dj = dL[j];
    if (sj == sq || sj == dq || dj == sq || dj == dq) {
      int pos = atomicAdd(&cnt[w], 1);
      if (pos < NBR_CAP) nbr[(size_t)qi * NBR_CAP + pos] = j;
    }
  }
  __syncthreads();
  if (lane == 0) deg[qi] = min(cnt[w], NBR_CAP);
}

// ---------------- Fused QKV projections with router gating -----------------
__global__ __launch_bounds__(256) void gemm_qkv_kernel(
    const float* __restrict__ nf, const float* __restrict__ ef,
    const float* __restrict__ ns, const float* __restrict__ es,
    const float* __restrict__ wq_n, const float* __restrict__ wk_n,
    const float* __restrict__ wv_n, const float* __restrict__ wq_e,
    const float* __restrict__ wk_e, const float* __restrict__ wv_e,
    const float* __restrict__ bq_n, const float* __restrict__ bk_n,
    const float* __restrict__ bv_n, const float* __restrict__ bq_e,
    const float* __restrict__ bk_e, const float* __restrict__ bv_e,
    float* __restrict__ qn, float* __restrict__ kn, float* __restrict__ vn,
    float* __restrict__ qe, float* __restrict__ ke, float* __restrict__ ve) {
  __shared__ float As[16][68];
  __shared__ float Bs[16][68];
  __shared__ float ss[64];
  int bx = blockIdx.x;
  int mat = blockIdx.y >> 1;
  int bn = (blockIdx.y & 1) * 64;
  bool edge = bx >= 32;
  int bm = edge ? (bx - 32) * 64 : bx * 64;
  const float* A = edge ? ef : nf;
  const float* sc = edge ? es : ns;
  const float* W;
  const float* bias;
  float* C;
  if (!edge) {
    if (mat == 0) { W = wq_n; bias = bq_n; C = qn; }
    else if (mat == 1) { W = wk_n; bias = bk_n; C = kn; }
    else { W = wv_n; bias = bv_n; C = vn; }
  } else {
    if (mat == 0) { W = wq_e; bias = bq_e; C = qe; }
    else if (mat == 1) { W = wk_e; bias = bk_e; C = ke; }
    else { W = wv_e; bias = bv_e; C = ve; }
  }
  int tid = threadIdx.x;
  if (tid < 64) ss[tid] = sc[bm + tid];
  __syncthreads();
  int tm = (tid >> 4) * 4, tn = (tid & 15) * 4;
  float4 acc[4] = {{0,0,0,0},{0,0,0,0},{0,0,0,0},{0,0,0,0}};
  for (int k0 = 0; k0 < DIM; k0 += 16) {
#pragma unroll
    for (int i = 0; i < 4; i++) {
      int e = i * 256 + tid;
      int r = e >> 4, kk = e & 15;
      As[kk][r] = A[(size_t)(bm + r) * DIM + k0 + kk] * ss[r];
      int kb = e >> 6, c = e & 63;
      Bs[kb][c] = W[(size_t)(k0 + kb) * DIM + bn + c];
    }
    __syncthreads();
#pragma unroll
    for (int kk = 0; kk < 16; kk++) {
      float4 a = *(const float4*)&As[kk][tm];
      float4 b = *(const float4*)&Bs[kk][tn];
      acc[0].x = fmaf(a.x, b.x, acc[0].x); acc[0].y = fmaf(a.x, b.y, acc[0].y);
      acc[0].z = fmaf(a.x, b.z, acc[0].z); acc[0].w = fmaf(a.x, b.w, acc[0].w);
      acc[1].x = fmaf(a.y, b.x, acc[1].x); acc[1].y = fmaf(a.y, b.y, acc[1].y);
      acc[1].z = fmaf(a.y, b.z, acc[1].z); acc[1].w = fmaf(a.y, b.w, acc[1].w);
      acc[2].x = fmaf(a.z, b.x, acc[2].x); acc[2].y = fmaf(a.z, b.y, acc[2].y);
      acc[2].z = fmaf(a.z, b.z, acc[2].z); acc[2].w = fmaf(a.z, b.w, acc[2].w);
      acc[3].x = fmaf(a.w, b.x, acc[3].x); acc[3].y = fmaf(a.w, b.y, acc[3].y);
      acc[3].z = fmaf(a.w, b.z, acc[3].z); acc[3].w = fmaf(a.w, b.w, acc[3].w);
    }
    __syncthreads();
  }
  float4 b4 = *(const float4*)&bias[bn + tn];
#pragma unroll
  for (int i = 0; i < 4; i++) {
    float4 r;
    r.x = acc[i].x + b4.x; r.y = acc[i].y + b4.y;
    r.z = acc[i].z + b4.z; r.w = acc[i].w + b4.w;
    *(float4*)&C[(size_t)(bm + tm + i) * DIM + bn + tn] = r;
  }
}

// ---------------- Shared 64x64 f32 GEMM tile body (K=128, float4 LDS) -------
__device__ __forceinline__ void gemm_body(
    float (&As)[16][68], float (&Bs)[16][68],
    const float* __restrict__ A, const float* __restrict__ B,
    int bm, int bn, int N, float4 (&acc)[4], int tid) {
  int tm = (tid >> 4) * 4, tn = (tid & 15) * 4;
  for (int k0 = 0; k0 < DIM; k0 += 16) {
#pragma unroll
    for (int i = 0; i < 4; i++) {
      int e = i * 256 + tid;
      int r = e >> 4, kk = e & 15;
      As[kk][r] = A[(size_t)(bm + r) * DIM + k0 + kk];
      int kb = e >> 6, c = e & 63;
      Bs[kb][c] = B[(size_t)(k0 + kb) * N + bn + c];
    }
    __syncthreads();
#pragma unroll
    for (int kk = 0; kk < 16; kk++) {
      float4 a = *(const float4*)&As[kk][tm];
      float4 b = *(const float4*)&Bs[kk][tn];
      acc[0].x = fmaf(a.x, b.x, acc[0].x); acc[0].y = fmaf(a.x, b.y, acc[0].y);
      acc[0].z = fmaf(a.x, b.z, acc[0].z); acc[0].w = fmaf(a.x, b.w, acc[0].w);
      acc[1].x = fmaf(a.y, b.x, acc[1].x); acc[1].y = fmaf(a.y, b.y, acc[1].y);
      acc[1].z = fmaf(a.y, b.z, acc[1].z); acc[1].w = fmaf(a.y, b.w, acc[1].w);
      acc[2].x = fmaf(a.z, b.x, acc[2].x); acc[2].y = fmaf(a.z, b.y, acc[2].y);
      acc[2].z = fmaf(a.z, b.z, acc[2].z); acc[2].w = fmaf(a.z, b.w, acc[2].w);
      acc[3].x = fmaf(a.w, b.x, acc[3].x); acc[3].y = fmaf(a.w, b.y, acc[3].y);
      acc[3].z = fmaf(a.w, b.z, acc[3].z); acc[3].w = fmaf(a.w, b.w, acc[3].w);
    }
    __syncthreads();
  }
}

// ---------------- Fused output projections (node + edge) --------------------
__global__ __launch_bounds__(256) void gemm_oproj_kernel(
    const float* __restrict__ aon, const float* __restrict__ aoe,
    const float* __restrict__ wo_n, const float* __restrict__ wo_e,
    const float* __restrict__ bo_n, const float* __restrict__ bo_e,
    float* __restrict__ pn, float* __restrict__ pe) {
  __shared__ float As[16][68];
  __shared__ float Bs[16][68];
  int bx = blockIdx.x;
  int bn = blockIdx.y * 64;
  bool edge = bx >= 32;
  int bm = edge ? (bx - 32) * 64 : bx * 64;
  const float* A = edge ? aoe : aon;
  const float* W = edge ? wo_e : wo_n;
  const float* bias = edge ? bo_e : bo_n;
  float* C = edge ? pe : pn;
  float4 acc[4] = {{0,0,0,0},{0,0,0,0},{0,0,0,0},{0,0,0,0}};
  int tid = threadIdx.x;
  gemm_body(As, Bs, A, W, bm, bn, DIM, acc, tid);
  int tm = (tid >> 4) * 4, tn = (tid & 15) * 4;
  float4 b4 = *(const float4*)&bias[bn + tn];
#pragma unroll
  for (int i = 0; i < 4; i++) {
    float4 r;
    r.x = acc[i].x + b4.x; r.y = acc[i].y + b4.y;
    r.z = acc[i].z + b4.z; r.w = acc[i].w + b4.w;
    *(float4*)&C[(size_t)(bm + tm + i) * DIM + bn + tn] = r;
  }
}

// ---------------- Gather GEMM: C = (NO[src]+NO[dst])@B + bias + EO ----------
__global__ __launch_bounds__(256) void gemm_msg_kernel(
    const float* __restrict__ NO, const int* __restrict__ src,
    const int* __restrict__ dst, const float* __restrict__ B,
    const float* __restrict__ bias, const float* __restrict__ EO,
    float* __restrict__ C) {
  __shared__ float As[16][68];
  __shared__ float Bs[16][68];
  int bm = blockIdx.x * 64, bn = blockIdx.y * 64;
  int tid = threadIdx.x;
  int tm = (tid >> 4) * 4, tn = (tid & 15) * 4;
  float4 acc[4] = {{0,0,0,0},{0,0,0,0},{0,0,0,0},{0,0,0,0}};
  for (int k0 = 0; k0 < DIM; k0 += 16) {
#pragma unroll
    for (int i = 0; i < 4; i++) {
      int e = i * 256 + tid;
      int r = e >> 4, kk = e & 15;
      int row = bm + r;
      int s0 = src[row], d0 = dst[row];
      As[kk][r] = NO[(size_t)s0 * DIM + k0 + kk] + NO[(size_t)d0 * DIM + k0 + kk];
      int kb = e >> 6, c = e & 63;
      Bs[kb][c] = B[(size_t)(k0 + kb) * DIM + bn + c];
    }
    __syncthreads();
#pragma unroll
    for (int kk = 0; kk < 16; kk++) {
      float4 a = *(const float4*)&As[kk][tm];
      float4 b = *(const float4*)&Bs[kk][tn];
      acc[0].x = fmaf(a.x, b.x, acc[0].x); acc[0].y = fmaf(a.x, b.y, acc[0].y);
      acc[0].z = fmaf(a.x, b.z, acc[0].z); acc[0].w = fmaf(a.x, b.w, acc[0].w);
      acc[1].x = fmaf(a.y, b.x, acc[1].x); acc[1].y = fmaf(a.y, b.y, acc[1].y);
      acc[1].z = fmaf(a.y, b.z, acc[1].z); acc[1].w = fmaf(a.y, b.w, acc[1].w);
      acc[2].x = fmaf(a.z, b.x, acc[2].x); acc[2].y = fmaf(a.z, b.y, acc[2].y);
      acc[2].z = fmaf(a.z, b.z, acc[2].z); acc[2].w = fmaf(a.z, b.w, acc[2].w);
      acc[3].x = fmaf(a.w, b.x, acc[3].x); acc[3].y = fmaf(a.w, b.y, acc[3].y);
      acc[3].z = fmaf(a.w, b.z, acc[3].z); acc[3].w = fmaf(a.w, b.w, acc[3].w);
    }
    __syncthreads();
  }
  float4 b4 = *(const float4*)&bias[bn + tn];
#pragma unroll
  for (int i = 0; i < 4; i++) {
    size_t idx = (size_t)(bm + tm + i) * DIM + bn + tn;
    float4 e4 = *(const float4*)&EO[idx];
    float4 r;
    r.x = acc[i].x + b4.x + e4.x; r.y = acc[i].y + b4.y + e4.y;
    r.z = acc[i].z + b4.z + e4.z; r.w = acc[i].w + b4.w + e4.w;
    *(float4*)&C[idx] = r;
  }
}

// ---------------- GELU GEMM: h = gelu(ue @ w_c1 + b), N=256 -----------------
__global__ __launch_bounds__(256) void gemm_gelu_kernel(
    const float* __restrict__ A, const float* __restrict__ B,
    const float* __restrict__ bias, float* __restrict__ C) {
  __shared__ float As[16][68];
  __shared__ float Bs[16][68];
  int bm = blockIdx.x * 64, bn = blockIdx.y * 64;
  int tid = threadIdx.x;
  float4 acc[4] = {{0,0,0,0},{0,0,0,0},{0,0,0,0},{0,0,0,0}};
  gemm_body(As, Bs, A, B, bm, bn, 256, acc, tid);
  int tm = (tid >> 4) * 4, tn = (tid & 15) * 4;
  float4 b4 = *(const float4*)&bias[bn + tn];
#pragma unroll
  for (int i = 0; i < 4; i++) {
    float vv[4] = {acc[i].x + b4.x, acc[i].y + b4.y, acc[i].z + b4.z,
                   acc[i].w + b4.w};
#pragma unroll
    for (int j = 0; j < 4; j++) {
      float v = vv[j];
      float u = 0.7978845608028654f * (v + 0.044715f * v * v * v);
      vv[j] = 0.5f * v * (1.0f + tanhf(u));
    }
    float4 r = {vv[0], vv[1], vv[2], vv[3]};
    *(float4*)&C[(size_t)(bm + tm + i) * 256 + bn + tn] = r;
  }
}

// ---------------- Node attention: register-tiled, key-split x2 --------------
// Round-5 post-mortem: LDS-read-bound (2.1M ds_read_b128 ~= 41us). Fix:
// thread owns TQ=4 queries x 16 dims (half split across lane pairs, one
// shfl_xor(16) completes the dot) -> each K/V float4 read serves 4 queries
// at half width = 4x less LDS traffic. Staging vectorized to float4.
// Scores tiny (|s|<~0.3) -> exp cannot overflow -> no running max.
// Thread map: e = tid&15 (key slot), half = (tid>>4)&1 (dim half),
// qg = tid>>5 (query group of TQ). Block: 32 queries x 512 keys.
__global__ __launch_bounds__(256) void attn_node_kernel(
    const float* __restrict__ Q, const float* __restrict__ K,
    const float* __restrict__ V, const int* __restrict__ kidx,
    const int* __restrict__ nkeptp, float* __restrict__ pacc,
    float* __restrict__ ps) {
  __shared__ float Ks[64][36];
  __shared__ float Vs[64][36];
  int h = blockIdx.y;
  int sp = blockIdx.z;
  int tid = threadIdx.x;
  int e = tid & 15;
  int half = (tid >> 4) & 1;
  int qg = tid >> 5;
  int qbase = blockIdx.x * QB + qg * TQ;
  int nkept = nkeptp[0];
  int spl = (nkept + NSPLIT - 1) / NSPLIT;
  int start = sp * spl;
  int end = min(start + spl, nkept);

  float4 qv[TQ][4];
#pragma unroll
  for (int t = 0; t < TQ; t++) {
    const float4* qp =
        (const float4*)(Q + (size_t)(qbase + t) * DIM + h * DH + half * 16);
#pragma unroll
    for (int i = 0; i < 4; i++) qv[t][i] = qp[i];
  }
  float s[TQ] = {0.f, 0.f, 0.f, 0.f};
  float4 acc[TQ][4];
#pragma unroll
  for (int t = 0; t < TQ; t++)
#pragma unroll
    for (int i = 0; i < 4; i++) acc[t][i] = make_float4(0.f, 0.f, 0.f, 0.f);

  for (int t0 = start; t0 < end; t0 += 64) {
    // stage 64 keys x 32 dims of K and V as float4 (2 fl4 each per thread)
#pragma unroll
    for (int i = 0; i < 2; i++) {
      int id = i * 256 + tid;  // 0..511
      int r = id >> 3, c4 = id & 7;
      int row = t0 + r;
      int ki = (row < end) ? kidx[row] : kidx[0];
      const float4* kp = (const float4*)(K + (size_t)ki * DIM + h * DH) + c4;
      const float4* vp = (const float4*)(V + (size_t)ki * DIM + h * DH) + c4;
      *(float4*)&Ks[r][c4 * 4] = *kp;
      *(float4*)&Vs[r][c4 * 4] = *vp;
    }
    __syncthreads();
    int nk = end - t0;
    if (nk > 64) nk = 64;
#pragma unroll
    for (int j8 = 0; j8 < 4; j8++) {
      int j = j8 * 16 + e;
      if (j < nk) {
        const float4* kr = (const float4*)&Ks[j][half * 16];
        float4 k0 = kr[0], k1 = kr[1], k2 = kr[2], k3 = kr[3];
        const float4* vr = (const float4*)&Vs[j][half * 16];
        float4 v0 = vr[0], v1 = vr[1], v2 = vr[2], v3 = vr[3];
#pragma unroll
        for (int t = 0; t < TQ; t++) {
          float d_ = qv[t][0].x * k0.x;
          d_ = fmaf(qv[t][0].y, k0.y, d_);
          d_ = fmaf(qv[t][0].z, k0.z, d_);
          d_ = fmaf(qv[t][0].w, k0.w, d_);
          d_ = fmaf(qv[t][1].x, k1.x, d_);
          d_ = fmaf(qv[t][1].y, k1.y, d_);
          d_ = fmaf(qv[t][1].z, k1.z, d_);
          d_ = fmaf(qv[t][1].w, k1.w, d_);
          d_ = fmaf(qv[t][2].x, k2.x, d_);
          d_ = fmaf(qv[t][2].y, k2.y, d_);
          d_ = fmaf(qv[t][2].z, k2.z, d_);
          d_ = fmaf(qv[t][2].w, k2.w, d_);
          d_ = fmaf(qv[t][3].x, k3.x, d_);
          d_ = fmaf(qv[t][3].y, k3.y, d_);
          d_ = fmaf(qv[t][3].z, k3.z, d_);
          d_ = fmaf(qv[t][3].w, k3.w, d_);
          d_ += __shfl_xor(d_, 16, 64);  // combine dim halves
          float p = __expf(d_ * SCALE);
          s[t] += p;
          acc[t][0].x = fmaf(p, v0.x, acc[t][0].x);
          acc[t][0].y = fmaf(p, v0.y, acc[t][0].y);
          acc[t][0].z = fmaf(p, v0.z, acc[t][0].z);
          acc[t][0].w = fmaf(p, v0.w, acc[t][0].w);
          acc[t][1].x = fmaf(p, v1.x, acc[t][1].x);
          acc[t][1].y = fmaf(p, v1.y, acc[t][1].y);
          acc[t][1].z = fmaf(p, v1.z, acc[t][1].z);
          acc[t][1].w = fmaf(p, v1.w, acc[t][1].w);
          acc[t][2].x = fmaf(p, v2.x, acc[t][2].x);
          acc[t][2].y = fmaf(p, v2.y, acc[t][2].y);
          acc[t][2].z = fmaf(p, v2.z, acc[t][2].z);
          acc[t][2].w = fmaf(p, v2.w, acc[t][2].w);
          acc[t][3].x = fmaf(p, v3.x, acc[t][3].x);
          acc[t][3].y = fmaf(p, v3.y, acc[t][3].y);
          acc[t][3].z = fmaf(p, v3.z, acc[t][3].z);
          acc[t][3].w = fmaf(p, v3.w, acc[t][3].w);
        }
      }
    }
    __syncthreads();
  }
  // reduce over the 16 key slots (lane bits 0..3); halves hold disjoint dims
#pragma unroll
  for (int t = 0; t < TQ; t++) {
#pragma unroll
    for (int o = 1; o <= 8; o <<= 1) {
      s[t] += __shfl_xor(s[t], o, 64);
#pragma unroll
      for (int i = 0; i < 4; i++) {
        acc[t][i].x += __shfl_xor(acc[t][i].x, o, 64);
        acc[t][i].y += __shfl_xor(acc[t][i].y, o, 64);
        acc[t][i].z += __shfl_xor(acc[t][i].z, o, 64);
        acc[t][i].w += __shfl_xor(acc[t][i].w, o, 64);
      }
    }
  }
  if (e == 0) {
#pragma unroll
    for (int t = 0; t < TQ; t++) {
      size_t idx = ((size_t)(qbase + t) * HEADS + h) * NSPLIT + sp;
      float4* pp = (float4*)(pacc + idx * 32 + half * 16);
#pragma unroll
      for (int i = 0; i < 4; i++) pp[i] = acc[t][i];
      if (half == 0) ps[idx] = s[t];
    }
  }
}

// ---------------- Node attention reduce: combine splits, normalize ----------
__global__ __launch_bounds__(256) void attn_node_reduce_kernel(
    const float* __restrict__ pacc, const float* __restrict__ ps,
    float* __restrict__ O) {
  int gid = blockIdx.x * 256 + threadIdx.x;
  int qh = gid >> 5, d = gid & 31;
  int q = qh >> 2, h = qh & 3;
  float ssum = 0.f, v = 0.f;
#pragma unroll
  for (int sp = 0; sp < NSPLIT; sp++) {
    size_t idx = (size_t)qh * NSPLIT + sp;
    ssum += ps[idx];
    v += pacc[idx * 32 + d];
  }
  O[(size_t)q * DIM + h * DH + d] = v / ssum;
}

// ---------------- Edge attention over neighbor lists ------------------------
// Block = 4 query edges; wave = head; lane = (q 2b | nbr-slot 2b | dim-qtr 2b).
__global__ __launch_bounds__(256) void attn_edge_kernel(
    const float* __restrict__ Q, const float* __restrict__ Km,
    const float* __restrict__ V, const int* __restrict__ nbr,
    const int* __restrict__ deg, float* __restrict__ O) {
  int h = threadIdx.x >> 6;
  int lane = threadIdx.x & 63;
  int ql = lane >> 4, j4 = (lane >> 2) & 3, g = lane & 3;
  int qi = blockIdx.x * 4 + ql;
  int dg = deg[qi];
  const float4* qp = (const float4*)(Q + (size_t)qi * DIM + h * DH + g * 8);
  float4 q0 = qp[0], q1 = qp[1];
  float s = 0.f;
  float4 a0 = make_float4(0.f, 0.f, 0.f, 0.f);
  float4 a1 = make_float4(0.f, 0.f, 0.f, 0.f);
  for (int c0 = 0; c0 < dg; c0 += 4) {
    int j = c0 + j4;
    bool act = j < dg;
    int ei = act ? nbr[(size_t)qi * NBR_CAP + j] : 0;
    const float4* kp = (const float4*)(Km + (size_t)ei * DIM + h * DH + g * 8);
    float4 k0 = kp[0], k1 = kp[1];
    float pd = q0.x * k0.x + q0.y * k0.y + q0.z * k0.z + q0.w * k0.w +
               q1.x * k1.x + q1.y * k1.y + q1.z * k1.z + q1.w * k1.w;
    pd += __shfl_xor(pd, 1, 64);
    pd += __shfl_xor(pd, 2, 64);  // full 32-dot in all 4 dim-qtr lanes
    float p = act ? __expf(pd * SCALE) : 0.f;
    s += p;
    const float4* vp = (const float4*)(V + (size_t)ei * DIM + h * DH + g * 8);
    float4 v0 = vp[0], v1 = vp[1];
    a0.x = fmaf(p, v0.x, a0.x); a0.y = fmaf(p, v0.y, a0.y);
    a0.z = fmaf(p, v0.z, a0.z); a0.w = fmaf(p, v0.w, a0.w);
    a1.x = fmaf(p, v1.x, a1.x); a1.y = fmaf(p, v1.y, a1.y);
    a1.z = fmaf(p, v1.z, a1.z); a1.w = fmaf(p, v1.w, a1.w);
  }
#pragma unroll
  for (int o = 4; o <= 8; o <<= 1) {
    s += __shfl_xor(s, o, 64);
    a0.x += __shfl_xor(a0.x, o, 64); a0.y += __shfl_xor(a0.y, o, 64);
    a0.z += __shfl_xor(a0.z, o, 64); a0.w += __shfl_xor(a0.w, o, 64);
    a1.x += __shfl_xor(a1.x, o, 64); a1.y += __shfl_xor(a1.y, o, 64);
    a1.z += __shfl_xor(a1.z, o, 64); a1.w += __shfl_xor(a1.w, o, 64);
  }
  if (j4 == 0) {
    float inv = 1.0f / s;
    float4* op = (float4*)(O + (size_t)qi * DIM + h * DH + g * 8);
    float4 r0 = {a0.x * inv, a0.y * inv, a0.z * inv, a0.w * inv};
    float4 r1 = {a1.x * inv, a1.y * inv, a1.z * inv, a1.w * inv};
    op[0] = r0;
    op[1] = r1;
  }
}

// ---------------- Final classifier GEMM: [4096,256]@[256,16]+b --------------
__global__ __launch_bounds__(256) void gemm_out_kernel(
    const float* __restrict__ Hm, const float* __restrict__ B,
    const float* __restrict__ bias, float* __restrict__ C) {
  __shared__ float Bs[256 * 16];
  int tid = threadIdx.x;
#pragma unroll
  for (int i = 0; i < 16; i++) Bs[i * 256 + tid] = B[i * 256 + tid];
  __syncthreads();
  int row = blockIdx.x * 16 + (tid >> 4);
  int col = tid & 15;
  const float* hp = Hm + (size_t)row * 256;
  float sacc = bias[col];
#pragma unroll 8
  for (int k = 0; k < 256; k++) sacc = fmaf(hp[k], Bs[k * 16 + col], sacc);
  C[(size_t)row * NCLS + col] = sacc;
}

extern "C" void kernel_launch(void* const* d_in, const int* in_sizes, int n_in,
                              void* d_out, int out_size, void* d_ws,
                              size_t ws_size, hipStream_t stream) {
  const float* nf = (const float*)d_in[0];
  const float* ef = (const float*)d_in[1];
  const int* ei = (const int*)d_in[2];
  const float* w_rn = (const float*)d_in[3];
  const float* b_rn = (const float*)d_in[4];
  const float* w_re = (const float*)d_in[5];
  const float* b_re = (const float*)d_in[6];
  const float* wq_n = (const float*)d_in[7];
  const float* bq_n = (const float*)d_in[8];
  const float* wk_n = (const float*)d_in[9];
  const float* bk_n = (const float*)d_in[10];
  const float* wv_n = (const float*)d_in[11];
  const float* bv_n = (const float*)d_in[12];
  const float* wo_n = (const float*)d_in[13];
  const float* bo_n = (const float*)d_in[14];
  const float* wq_e = (const float*)d_in[15];
  const float* bq_e = (const float*)d_in[16];
  const float* wk_e = (const float*)d_in[17];
  const float* bk_e = (const float*)d_in[18];
  const float* wv_e = (const float*)d_in[19];
  const float* bv_e = (const float*)d_in[20];
  const float* wo_e = (const float*)d_in[21];
  const float* bo_e = (const float*)d_in[22];
  const float* w_ne = (const float*)d_in[23];
  const float* b_ne = (const float*)d_in[24];
  const float* w_c1 = (const float*)d_in[25];
  const float* b_c1 = (const float*)d_in[26];
  const float* w_c2 = (const float*)d_in[27];
  const float* b_c2 = (const float*)d_in[28];

  const int* src = ei;
  const int* dst = ei + N_EDGES;

  float* ws = (float*)d_ws;
  size_t o = 0;
  float* ns = ws + o;   o += 2048;
  float* es = ws + o;   o += 4096;
  int* kidx = (int*)(ws + o); o += 2048;
  int* nkept = (int*)(ws + o); o += 64;
  int* nbr = (int*)(ws + o); o += (size_t)N_EDGES * NBR_CAP;
  int* degp = (int*)(ws + o); o += N_EDGES;
  float* qn = ws + o;   o += (size_t)N_NODES * DIM;
  float* kn = ws + o;   o += (size_t)N_NODES * DIM;
  float* vn = ws + o;   o += (size_t)N_NODES * DIM;
  float* qe = ws + o;   o += (size_t)N_EDGES * DIM;
  float* ke = ws + o;   o += (size_t)N_EDGES * DIM;
  float* ve = ws + o;   o += (size_t)N_EDGES * DIM;
  float* aon = ws + o;  o += (size_t)N_NODES * DIM;
  float* aoe = ws + o;  o += (size_t)N_EDGES * DIM;
  float* pn = ws + o;   o += (size_t)N_NODES * DIM;
  float* pe = ws + o;   o += (size_t)N_EDGES * DIM;
  float* ue = ws + o;   o += (size_t)N_EDGES * DIM;
  float* hb = ws + o;   o += (size_t)N_EDGES * 2 * DIM;
  float* ps = ws + o;   o += (size_t)N_NODES * HEADS * NSPLIT;
  float* pacc = hb;  // alias: pacc lifetime (steps 5-6) ends before hb (10-11)

  // 1. router scores
  score_kernel<<<dim3((N_NODES + N_EDGES) / 4), 256, 0, stream>>>(
      nf, ef, w_rn, b_rn, w_re, b_re, ns, es);
  // 2. top-k threshold + compacted kept-key list
  topk_kernel<<<1, 256, 0, stream>>>(ns, kidx, nkept);
  // 3. line-graph neighbor lists
  build_nbr_kernel<<<dim3(N_EDGES / 16), 1024, 0, stream>>>(src, dst, nbr,
                                                            degp);
  // 4. all six QKV projections (router gating fused into A-stage)
  gemm_qkv_kernel<<<dim3(96, 6), 256, 0, stream>>>(
      nf, ef, ns, es, wq_n, wk_n, wv_n, wq_e, wk_e, wv_e,
      bq_n, bk_n, bv_n, bq_e, bk_e, bv_e, qn, kn, vn, qe, ke, ve);
  // 5-6. node attention (register-tiled, key-split x2) + reduce
  attn_node_kernel<<<dim3(N_NODES / QB, HEADS, NSPLIT), 256, 0, stream>>>(
      qn, kn, vn, kidx, nkept, pacc, ps);
  attn_node_reduce_kernel<<<dim3(N_NODES * HEADS * DH / 256), 256, 0,
                            stream>>>(pacc, ps, aon);
  // 7. edge attention
  attn_edge_kernel<<<dim3(N_EDGES / 4), 256, 0, stream>>>(
      qe, ke, ve, nbr, degp, aoe);
  // 8. both output projections, one launch
  gemm_oproj_kernel<<<dim3(96, 2), 256, 0, stream>>>(
      aon, aoe, wo_n, wo_e, bo_n, bo_e, pn, pe);
  // 9. updated_edges = pe + (pn[src]+pn[dst]) @ w_ne + b_ne
  gemm_msg_kernel<<<dim3(64, 2), 256, 0, stream>>>(pn, src, dst, w_ne, b_ne,
                                                   pe, ue);
  // 10. h = gelu(ue @ w_c1 + b_c1)
  gemm_gelu_kernel<<<dim3(64, 4), 256, 0, stream>>>(ue, w_c1, b_c1, hb);
  // 11. out = h @ w_c2 + b_c2
  gemm_out_kernel<<<dim3(N_EDGES / 16), 256, 0, stream>>>(hb, w_c2, b_c2,
                                                          (float*)d_out);
}